// Round 17
// baseline (1208.510 us; speedup 1.0000x reference)
//
#include <hip/hip_runtime.h>
#include <cstdint>

#define HW 131072        // H*W
#define S_ELEMS 16777216 // B*C*H*W

typedef __attribute__((ext_vector_type(8))) _Float16 f16x8;
typedef __attribute__((ext_vector_type(4))) _Float16 f16x4;
typedef __attribute__((ext_vector_type(4))) float f32x4;

__device__ __forceinline__ float h2f(unsigned short u) {
  return (float)__builtin_bit_cast(_Float16, u);
}
__device__ __forceinline__ unsigned short f2h(float f) {
  return __builtin_bit_cast(unsigned short, (_Float16)f);
}
// M32 bank swizzle: XOR col 8-blocks by row-class; kills j/j+8/j+16/j+24 bank aliasing
// while keeping 8-float blocks contiguous (float4-aligned reads still valid).
__device__ __forceinline__ int msw(int r, int c) {
  return r * 68 + (c ^ (((r >> 3) & 3) << 3));
}

// ---------------- BN stats stage 1: partial sums (2 sides x 64 c x 16 slabs) ----------------
__global__ __launch_bounds__(256) void bn_part_k(const float* __restrict__ xL,
                                                 const float* __restrict__ xR,
                                                 float2* __restrict__ partial) {
  int bid = blockIdx.x;
  int side = bid >> 10, rest = bid & 1023;
  int c = rest >> 4, sl = rest & 15;
  const float* x = side ? xR : xL;
  const float4* p = (const float4*)(x + ((size_t)((sl >> 3) * 64 + c)) * HW + (size_t)(sl & 7) * 16384);
  float s1 = 0.f, s2 = 0.f;
  for (int i = threadIdx.x; i < 4096; i += 256) {
    float4 v = p[i];
    s1 += v.x + v.y + v.z + v.w;
    s2 += v.x * v.x + v.y * v.y + v.z * v.z + v.w * v.w;
  }
  for (int m = 32; m; m >>= 1) {
    s1 += __shfl_xor(s1, m, 64);
    s2 += __shfl_xor(s2, m, 64);
  }
  __shared__ float r1[4], r2[4];
  int wv = threadIdx.x >> 6;
  if ((threadIdx.x & 63) == 0) { r1[wv] = s1; r2[wv] = s2; }
  __syncthreads();
  if (threadIdx.x == 0) {
    partial[bid] = make_float2(r1[0] + r1[1] + r1[2] + r1[3], r2[0] + r2[1] + r2[2] + r2[3]);
  }
}

// ---------------- BN stats stage 2: finalize scale/shift ----------------
__global__ __launch_bounds__(128) void bn_fin_k(const float2* __restrict__ partial,
                                                const float* __restrict__ gamma,
                                                const float* __restrict__ beta,
                                                float* __restrict__ stats) {
  int tid = threadIdx.x;  // 0..127: side*64 + c
  int side = tid >> 6, c = tid & 63;
  float s1 = 0.f, s2 = 0.f;
  const float2* p = partial + (side * 1024 + c * 16);
  for (int s = 0; s < 16; ++s) { float2 v = p[s]; s1 += v.x; s2 += v.y; }
  float mu = s1 / 262144.f;
  float var = s2 / 262144.f - mu * mu;
  float rs = rsqrtf(var + 1e-5f);
  float sc = rs * gamma[c];
  stats[side * 128 + c] = sc;
  stats[side * 128 + 64 + c] = beta[c] - mu * sc;
}

// ---------------- conv1: tiled grouped 3x3 (8x32 tile), BN-in + leaky, fp16 LDS + fp16 out --
__global__ __launch_bounds__(256, 6) void conv1_k(const float* __restrict__ xL,
                                                  const float* __restrict__ xR,
                                                  const float* __restrict__ wgt,
                                                  const float* __restrict__ bias,
                                                  const float* __restrict__ stats,
                                                  unsigned short* __restrict__ tL,
                                                  unsigned short* __restrict__ tR) {
  __shared__ __align__(16) unsigned short sInH[16 * 10 * 36];  // bn(x) fp16 (11.5KB)
  __shared__ __align__(16) float sW[16 * 16 * 3 * 4];  // [o][ci][kh] float4 {w0,w1,w2,pad}
  __shared__ float sSc[16], sSh[16];
  int bid = blockIdx.x;
  int side = bid >> 12, rest = bid & 4095;
  int tw = rest & 15, th = (rest >> 4) & 31, g = (rest >> 9) & 3, b = rest >> 11;
  const float* in = side ? xR : xL;
  unsigned short* out = side ? tR : tL;
  const float* ss = stats + side * 128;
  int tid = threadIdx.x;
  for (int e = tid; e < 2304; e += 256) {
    int o = e / 144, rem = e - o * 144, ci = rem / 9, k = rem - ci * 9;
    sW[((o * 16 + ci) * 3 + k / 3) * 4 + k % 3] = wgt[(g * 16 + o) * 144 + rem];
  }
  if (tid < 16) { sSc[tid] = ss[g * 16 + tid]; sSh[tid] = ss[64 + g * 16 + tid]; }
  __syncthreads();  // RACE FIX: sSc/sSh visible before staging reads
  int h0 = th * 8 - 1, w0 = tw * 32 - 1;
  const float* inb = in + ((size_t)(b * 64 + g * 16)) * HW;
  for (int e = tid; e < 5440; e += 256) {
    int ci = e / 340, rem = e - ci * 340, r = rem / 34, c = rem - r * 34;
    int h = h0 + r, w = w0 + c;
    unsigned short v = 0;
    if ((unsigned)h < 256u && (unsigned)w < 512u) {
      v = f2h(inb[(size_t)ci * HW + h * 512 + w] * sSc[ci] + sSh[ci]);
    }
    sInH[ci * 360 + r * 36 + c] = v;
  }
  __syncthreads();
  int oh = tid >> 6;  // 0..3 output-channel quad
  int pxi = tid & 63;
  int row = pxi >> 3, col = (pxi & 7) * 4;
  float acc[4][4];
#pragma unroll
  for (int o = 0; o < 4; ++o) {
    float bz = bias[g * 16 + oh * 4 + o];
#pragma unroll
    for (int p = 0; p < 4; ++p) acc[o][p] = bz;
  }
  for (int ci = 0; ci < 16; ++ci) {
    float v[3][6];
    const unsigned short* base = sInH + ci * 360 + row * 36 + col;
#pragma unroll
    for (int kh = 0; kh < 3; ++kh) {
      ushort4 u0 = *(const ushort4*)(base + kh * 36);
      ushort2 u1 = *(const ushort2*)(base + kh * 36 + 4);
      v[kh][0] = h2f(u0.x); v[kh][1] = h2f(u0.y); v[kh][2] = h2f(u0.z);
      v[kh][3] = h2f(u0.w); v[kh][4] = h2f(u1.x); v[kh][5] = h2f(u1.y);
    }
    const float4* wb = (const float4*)sW + ((oh * 4) * 16 + ci) * 3;
#pragma unroll
    for (int o = 0; o < 4; ++o) {
      const float4* wo = wb + o * 48;
#pragma unroll
      for (int kh = 0; kh < 3; ++kh) {
        float4 wv = wo[kh];
#pragma unroll
        for (int p = 0; p < 4; ++p)
          acc[o][p] += wv.x * v[kh][p] + wv.y * v[kh][p + 1] + wv.z * v[kh][p + 2];
      }
    }
  }
  int h = th * 8 + row, wcol = tw * 32 + col;
#pragma unroll
  for (int o = 0; o < 4; ++o) {
    int cg = g * 16 + oh * 4 + o;
    size_t off = ((size_t)(b * 64 + cg)) * HW + h * 512 + wcol;
    ushort4 r4;
#pragma unroll
    for (int p = 0; p < 4; ++p) {
      float a = acc[o][p];
      a = a > 0.f ? a : 0.1f * a;
      ((unsigned short*)&r4)[p] = f2h(a);
    }
    *(ushort4*)(out + off) = r4;
  }
}

// ---------------- fused conv2 + residual + qkv(MFMA); both sides ----------------
// LDS: sBuf unions {fp16 conv1-out tile [16][10][36] (11.5KB)} then {fp32 sR[16][260] (16.6KB)}
__global__ __launch_bounds__(256, 4) void conv2_qkv_k(
    const unsigned short* __restrict__ tL, const unsigned short* __restrict__ tR,
    const float* __restrict__ xL, const float* __restrict__ xR,
    const float* __restrict__ w2g, const float* __restrict__ b2g,
    const float* __restrict__ wq, const float* __restrict__ bq,
    const float* __restrict__ stats,
    float* __restrict__ qnL, float* __restrict__ qnR,
    float* __restrict__ knL, float* __restrict__ knR,
    unsigned short* __restrict__ vnL, unsigned short* __restrict__ vnR) {
  __shared__ __align__(16) float sBuf[4160];         // 16.6KB union
  __shared__ __align__(16) float sW2[16 * 16 * 3 * 4];
  __shared__ __align__(16) float sWq[768];
  __shared__ float sB2[16], sBq[48], sSc[16], sSh[16];
  unsigned short* sInH = (unsigned short*)sBuf;      // [16][10][36] fp16
  float* sR = sBuf;                                  // [16][260] fp32 (after conv2)

  int bid = blockIdx.x;
  int side = bid >> 12, rest = bid & 4095;
  int tw = rest & 15, th = (rest >> 4) & 31, g = (rest >> 9) & 3, b = rest >> 11;
  const unsigned short* t = side ? tR : tL;
  const float* x = side ? xR : xL;
  float* qn = side ? qnR : qnL;
  float* kn = side ? knR : knL;
  unsigned short* vn = side ? vnR : vnL;
  const float* ss = stats + side * 128;
  int tid = threadIdx.x;

  // early residual prefetch (T14): hide HBM latency under stage + conv2
  int oh = tid >> 6;
  int pxi = tid & 63;
  int row = pxi >> 3, col = (pxi & 7) * 4;
  float4 resx[4];
  {
    int h = th * 8 + row, wcol = tw * 32 + col;
#pragma unroll
    for (int o = 0; o < 4; ++o) {
      int cg = g * 16 + oh * 4 + o;
      resx[o] = *(const float4*)(x + ((size_t)(b * 64 + cg)) * HW + h * 512 + wcol);
    }
  }

  for (int e = tid; e < 2304; e += 256) {
    int o = e / 144, rem = e - o * 144, ci = rem / 9, k = rem - ci * 9;
    sW2[((o * 16 + ci) * 3 + k / 3) * 4 + k % 3] = w2g[(g * 16 + o) * 144 + rem];
  }
  for (int e = tid; e < 768; e += 256) {
    int oo = e >> 4, ci = e & 15;
    sWq[e] = wq[(g * 48 + oo) * 16 + ci];
  }
  if (tid < 48) sBq[tid] = bq[g * 48 + tid];
  if (tid < 16) {
    sB2[tid] = b2g[g * 16 + tid];
    sSc[tid] = ss[g * 16 + tid];
    sSh[tid] = ss[64 + g * 16 + tid];
  }
  __syncthreads();  // LDS scalars visible before any use (race-fix discipline)

  // ---- stage conv1-out tile (1-halo) from global fp16 -> LDS fp16 ----
  int h0 = th * 8 - 1, w0 = tw * 32 - 1;
  const unsigned short* inb = t + ((size_t)(b * 64 + g * 16)) * HW;
  for (int e = tid; e < 5440; e += 256) {
    int ci = e / 340, rem = e - ci * 340, r = rem / 34, c = rem - r * 34;
    int h = h0 + r, w = w0 + c;
    unsigned short v = 0;
    if ((unsigned)h < 256u && (unsigned)w < 512u) {
      v = inb[(size_t)ci * HW + h * 512 + w];
    }
    sInH[ci * 360 + r * 36 + c] = v;
  }
  __syncthreads();

  // ---- conv2 (4 oc per thread, fp16 LDS reads) + residual ----
  float acc[4][4];
#pragma unroll
  for (int o = 0; o < 4; ++o) {
    float bz = sB2[oh * 4 + o];
#pragma unroll
    for (int p = 0; p < 4; ++p) acc[o][p] = bz;
  }
  for (int ci = 0; ci < 16; ++ci) {
    float v[3][6];
    const unsigned short* base = sInH + ci * 360 + row * 36 + col;
#pragma unroll
    for (int kh = 0; kh < 3; ++kh) {
      ushort4 u0 = *(const ushort4*)(base + kh * 36);
      ushort2 u1 = *(const ushort2*)(base + kh * 36 + 4);
      v[kh][0] = h2f(u0.x); v[kh][1] = h2f(u0.y); v[kh][2] = h2f(u0.z);
      v[kh][3] = h2f(u0.w); v[kh][4] = h2f(u1.x); v[kh][5] = h2f(u1.y);
    }
    const float4* wb = (const float4*)sW2 + ((oh * 4) * 16 + ci) * 3;
#pragma unroll
    for (int o = 0; o < 4; ++o) {
      const float4* wo = wb + o * 48;
#pragma unroll
      for (int kh = 0; kh < 3; ++kh) {
        float4 wv = wo[kh];
#pragma unroll
        for (int p = 0; p < 4; ++p)
          acc[o][p] += wv.x * v[kh][p] + wv.y * v[kh][p + 1] + wv.z * v[kh][p + 2];
      }
    }
  }
#pragma unroll
  for (int o = 0; o < 4; ++o) {
    float sc = sSc[oh * 4 + o], sh = sSh[oh * 4 + o];
#pragma unroll
    for (int p = 0; p < 4; ++p) acc[o][p] += ((float*)&resx[o])[p] * sc + sh;
  }
  __syncthreads();  // all sInH reads done; safe to overlay sR

  // ---- write r-tile into sR[16][260] ----
#pragma unroll
  for (int o = 0; o < 4; ++o) {
    float* dst = sR + (oh * 4 + o) * 260 + row * 32 + col;
#pragma unroll
    for (int p = 0; p < 4; ++p) dst[p] = acc[o][p];
  }
  __syncthreads();

  // ---- qkv via split-fp16 MFMA: O[48][256] = W[48][16] . r[16][256] ----
  {
    const int lane = tid & 63, wv = tid >> 6;
    const int l15 = lane & 15, lg = lane >> 4;
    f16x4 WH[3], WL[3];
#pragma unroll
    for (int rt = 0; rt < 3; ++rt) {
      float4 wvv = *(const float4*)(sWq + (rt * 16 + l15) * 16 + 4 * lg);
#pragma unroll
      for (int i = 0; i < 4; ++i) {
        float f = ((float*)&wvv)[i];
        _Float16 h = (_Float16)f;
        WH[rt][i] = h;
        WL[rt][i] = (_Float16)(f - (float)h);
      }
    }
#pragma unroll
    for (int j = 0; j < 4; ++j) {
      int ct = 4 * wv + j;
      f16x4 rh, rl;
#pragma unroll
      for (int i = 0; i < 4; ++i) {
        float f = sR[(4 * lg + i) * 260 + ct * 16 + l15];
        _Float16 h = (_Float16)f;
        rh[i] = h;
        rl[i] = (_Float16)(f - (float)h);
      }
      int px = ct * 16 + l15;
      int hpix = th * 8 + (px >> 5), wpix = tw * 32 + (px & 31);
      size_t pxbase = ((size_t)b * HW + hpix * 512 + wpix) * 64;
#pragma unroll
      for (int rt = 0; rt < 3; ++rt) {
        f32x4 a;
#pragma unroll
        for (int r = 0; r < 4; ++r) a[r] = sBq[rt * 16 + 4 * lg + r];
        a = __builtin_amdgcn_mfma_f32_16x16x16f16(WH[rt], rh, a, 0, 0, 0);
        a = __builtin_amdgcn_mfma_f32_16x16x16f16(WH[rt], rl, a, 0, 0, 0);
        a = __builtin_amdgcn_mfma_f32_16x16x16f16(WL[rt], rh, a, 0, 0, 0);
        int ob = g * 48 + rt * 16 + 4 * lg;
        if (ob < 64) {
          *(float4*)(qn + pxbase + ob) = *(float4*)&a;
        } else if (ob < 128) {
          *(float4*)(kn + pxbase + (ob - 64)) = *(float4*)&a;
        } else {
          uint2 pk;
          pk.x = (uint32_t)f2h(a[0]) | ((uint32_t)f2h(a[1]) << 16);
          pk.y = (uint32_t)f2h(a[2]) | ((uint32_t)f2h(a[3]) << 16);
          *(uint2*)(vn + pxbase + (ob - 128)) = pk;
        }
      }
    }
  }
}

// ---------------- fused per-window attention: split-fp16 MFMA, all-NHWC, XCD swizzle ----
__global__ __launch_bounds__(256, 4) void attn_k(
    const float* __restrict__ qLn, const float* __restrict__ qRn,  // NHWC fp32
    const float* __restrict__ kLn, const float* __restrict__ kRn,  // NHWC fp32
    const unsigned short* __restrict__ vLn, const unsigned short* __restrict__ vRn, // NHWC fp16
    const float* __restrict__ dL, const float* __restrict__ dR,
    const float* __restrict__ xL, const float* __restrict__ xR,
    float* outL, float* outR) {
  // XCD-aware swizzle: consecutive windows -> same XCD L2 (4096 % 8 == 0, bijective)
  const int orig = blockIdx.x;
  const int n = (orig & 7) * 512 + (orig >> 3);
  const int b = n >> 11, hb = (n >> 6) & 31, wb = n & 63;
  const int tid = threadIdx.x;
  const int lane = tid & 63, w = tid >> 6;
  const int l15 = lane & 15, lg = lane >> 4;

  // K hi/lo (stride 72, fp16) — region reused after QK^T as fp32 M (stride 68, msw-swizzled)
  __shared__ __align__(16) unsigned short sK[4 * 64 * 72];   // 36864 B
  __shared__ float meanA[8], meanB[8], qsA[64], qsB[64], mapL[64], mapR[64];
  unsigned short* KHA = sK;
  unsigned short* KLA = sK + 64 * 72;
  unsigned short* KHB = sK + 2 * 64 * 72;
  unsigned short* KLB = sK + 3 * 64 * 72;
  float* M32A = (float*)sK;           // [64][68] msw layout
  float* M32B = (float*)sK + 64 * 68; // [64][68]

  const float* dLb = dL + (size_t)b * HW;
  const float* dRb = dR + (size_t)b * HW;
  const size_t nb = (size_t)b * HW;

  // ---- K gather (NHWC): 2 iters, 8 channels per thread per dir ----
  const int cc0 = (wb & 7) * 8;
#pragma unroll
  for (int it = 0; it < 2; ++it) {
    int slot = tid + 256 * it;           // 0..511
    int c2 = slot & 63, k8 = slot >> 6;  // k8 0..7
    int hh = 4 * c2 + (hb >> 3);
    int ww = (hb & 7) * 64 + k8 * 8 + (wb >> 3);
    int dpos = hh * 512 + ww;
    int iwr = ww - (int)dLb[dpos]; iwr = min(max(iwr, 0), 511);
    int iwl = ww + (int)dRb[dpos]; iwl = min(max(iwl, 0), 511);
    const float* pr = kRn + (nb + hh * 512 + iwr) * 64 + cc0;
    const float* pl = kLn + (nb + hh * 512 + iwl) * 64 + cc0;
    float fr[8], fl[8];
    *(float4*)&fr[0] = *(const float4*)pr;
    *(float4*)&fr[4] = *(const float4*)(pr + 4);
    *(float4*)&fl[0] = *(const float4*)pl;
    *(float4*)&fl[4] = *(const float4*)(pl + 4);
#pragma unroll
    for (int kl = 0; kl < 8; ++kl) {
      int k = 8 * k8 + kl;
      unsigned short hr = f2h(fr[kl]), hl = f2h(fl[kl]);
      KHA[k * 72 + c2] = hr; KLA[k * 72 + c2] = f2h(fr[kl] - h2f(hr));
      KHB[k * 72 + c2] = hl; KLB[k * 72 + c2] = f2h(fl[kl] - h2f(hl));
    }
  }

  // ---- Q load (NHWC fp32) + hi/lo split ----
  const int jr = 16 * w + l15;
  const int hp = hb * 8 + (jr >> 3), wp = wb * 8 + (jr & 7);
  const int gpix = hp * 512 + wp;
  const float* qlp = qLn + (nb + gpix) * 64;
  const float* qrp = qRn + (nb + gpix) * 64;
  float qv0[8], qv1[8], qw0[8], qw1[8];
  *(float4*)&qv0[0] = *(const float4*)(qlp + 8 * lg);
  *(float4*)&qv0[4] = *(const float4*)(qlp + 8 * lg + 4);
  *(float4*)&qv1[0] = *(const float4*)(qlp + 32 + 8 * lg);
  *(float4*)&qv1[4] = *(const float4*)(qlp + 32 + 8 * lg + 4);
  *(float4*)&qw0[0] = *(const float4*)(qrp + 8 * lg);
  *(float4*)&qw0[4] = *(const float4*)(qrp + 8 * lg + 4);
  *(float4*)&qw1[0] = *(const float4*)(qrp + 32 + 8 * lg);
  *(float4*)&qw1[4] = *(const float4*)(qrp + 32 + 8 * lg + 4);
  f16x8 qah0, qal0, qah1, qal1, qbh0, qbl0, qbh1, qbl1;
#pragma unroll
  for (int e = 0; e < 8; ++e) {
    _Float16 h;
    h = (_Float16)qv0[e]; qah0[e] = h; qal0[e] = (_Float16)(qv0[e] - (float)h);
    h = (_Float16)qv1[e]; qah1[e] = h; qal1[e] = (_Float16)(qv1[e] - (float)h);
    h = (_Float16)qw0[e]; qbh0[e] = h; qbl0[e] = (_Float16)(qw0[e] - (float)h);
    h = (_Float16)qw1[e]; qbh1[e] = h; qbl1[e] = (_Float16)(qw1[e] - (float)h);
  }

  // ---- V fragments (NHWC fp16: one b128 per (h,dir)) ----
  int4 vAr[2], vBr[2];
  {
    const int cv = 16 * w + l15;
#pragma unroll
    for (int h = 0; h < 2; ++h) {
      int hi = 4 * h + lg;
      int hh = 4 * cv + (hb >> 3);
      int ww = (hb & 7) * 64 + hi * 8 + (wb >> 3);
      int dpos = hh * 512 + ww;
      int iwr = ww - (int)dLb[dpos]; iwr = min(max(iwr, 0), 511);
      int iwl = ww + (int)dRb[dpos]; iwl = min(max(iwl, 0), 511);
      vAr[h] = *(const int4*)(vRn + (nb + hh * 512 + iwr) * 64 + cc0);
      vBr[h] = *(const int4*)(vLn + (nb + hh * 512 + iwl) * 64 + cc0);
    }
  }
  __syncthreads();  // B1: K staged

  // ---- K means per (dir,hi) over (wi,c): exact = hi+lo ----
  {
    int grp = tid >> 4, i = tid & 15;
    int dir = grp >> 3, hi = grp & 7;
    int off0 = (8 * hi + (i >> 1)) * 72 + (i & 1) * 32;
    const unsigned short* srcH = (dir ? KHB : KHA) + off0;
    const unsigned short* srcL = (dir ? KLB : KLA) + off0;
    float s = 0.f;
#pragma unroll
    for (int q = 0; q < 32; ++q) s += h2f(srcH[q]) + h2f(srcL[q]);
    for (int m = 8; m; m >>= 1) s += __shfl_xor(s, m, 64);
    if (i == 0) (dir ? meanB : meanA)[hi] = s * (1.f / 512.f);
  }
  // ---- qsum[j] (fp32 exact) ----
  {
    float sa = 0.f, sb = 0.f;
#pragma unroll
    for (int e = 0; e < 8; ++e) {
      sa += qv0[e] + qv1[e];
      sb += qw0[e] + qw1[e];
    }
    sa += __shfl_xor(sa, 16, 64); sa += __shfl_xor(sa, 32, 64);
    sb += __shfl_xor(sb, 16, 64); sb += __shfl_xor(sb, 32, 64);
    if (lane < 16) { qsA[jr] = sa; qsB[jr] = sb; }
  }
  __syncthreads();  // B2: means + qsums ready

  // ---- QK^T via split-fp16 MFMA: q.k ~= qh.kh + qh.kl + ql.kh ----
  f32x4 sA[4], sB[4];
#pragma unroll
  for (int t = 0; t < 4; ++t) { sA[t] = (f32x4){0.f, 0.f, 0.f, 0.f}; sB[t] = sA[t]; }
#pragma unroll
  for (int t = 0; t < 4; ++t) {
    int ro = (16 * t + l15) * 72 + 8 * lg;
    f16x8 kh0 = *(const f16x8*)(KHA + ro);
    f16x8 kl0 = *(const f16x8*)(KLA + ro);
    f16x8 kh1 = *(const f16x8*)(KHA + ro + 32);
    f16x8 kl1 = *(const f16x8*)(KLA + ro + 32);
    sA[t] = __builtin_amdgcn_mfma_f32_16x16x32_f16(qah0, kh0, sA[t], 0, 0, 0);
    sA[t] = __builtin_amdgcn_mfma_f32_16x16x32_f16(qah0, kl0, sA[t], 0, 0, 0);
    sA[t] = __builtin_amdgcn_mfma_f32_16x16x32_f16(qal0, kh0, sA[t], 0, 0, 0);
    sA[t] = __builtin_amdgcn_mfma_f32_16x16x32_f16(qah1, kh1, sA[t], 0, 0, 0);
    sA[t] = __builtin_amdgcn_mfma_f32_16x16x32_f16(qah1, kl1, sA[t], 0, 0, 0);
    sA[t] = __builtin_amdgcn_mfma_f32_16x16x32_f16(qal1, kh1, sA[t], 0, 0, 0);
    f16x8 mh0 = *(const f16x8*)(KHB + ro);
    f16x8 ml0 = *(const f16x8*)(KLB + ro);
    f16x8 mh1 = *(const f16x8*)(KHB + ro + 32);
    f16x8 ml1 = *(const f16x8*)(KLB + ro + 32);
    sB[t] = __builtin_amdgcn_mfma_f32_16x16x32_f16(qbh0, mh0, sB[t], 0, 0, 0);
    sB[t] = __builtin_amdgcn_mfma_f32_16x16x32_f16(qbh0, ml0, sB[t], 0, 0, 0);
    sB[t] = __builtin_amdgcn_mfma_f32_16x16x32_f16(qbl0, mh0, sB[t], 0, 0, 0);
    sB[t] = __builtin_amdgcn_mfma_f32_16x16x32_f16(qbh1, mh1, sB[t], 0, 0, 0);
    sB[t] = __builtin_amdgcn_mfma_f32_16x16x32_f16(qbh1, ml1, sB[t], 0, 0, 0);
    sB[t] = __builtin_amdgcn_mfma_f32_16x16x32_f16(qbl1, mh1, sB[t], 0, 0, 0);
  }
  // ---- mean-fold correction + in-register softmax over k ----
  {
    float qra[4], qrb2[4];
#pragma unroll
    for (int reg = 0; reg < 4; ++reg) {
      qra[reg] = qsA[16 * w + 4 * lg + reg];
      qrb2[reg] = qsB[16 * w + 4 * lg + reg];
    }
#pragma unroll
    for (int t = 0; t < 4; ++t) {
      float mA_ = meanA[2 * t + (l15 >> 3)];
      float mB_ = meanB[2 * t + (l15 >> 3)];
#pragma unroll
      for (int reg = 0; reg < 4; ++reg) {
        sA[t][reg] -= qra[reg] * mA_;
        sB[t][reg] -= qrb2[reg] * mB_;
      }
    }
#pragma unroll
    for (int reg = 0; reg < 4; ++reg) {
      float ma = sA[0][reg], mb = sB[0][reg];
#pragma unroll
      for (int t = 1; t < 4; ++t) { ma = fmaxf(ma, sA[t][reg]); mb = fmaxf(mb, sB[t][reg]); }
#pragma unroll
      for (int m = 1; m <= 8; m <<= 1) {
        ma = fmaxf(ma, __shfl_xor(ma, m, 64));
        mb = fmaxf(mb, __shfl_xor(mb, m, 64));
      }
      float sa = 0.f, sb = 0.f;
#pragma unroll
      for (int t = 0; t < 4; ++t) {
        float ea = __expf(sA[t][reg] - ma), eb = __expf(sB[t][reg] - mb);
        sA[t][reg] = ea; sB[t][reg] = eb;
        sa += ea; sb += eb;
      }
#pragma unroll
      for (int m = 1; m <= 8; m <<= 1) {
        sa += __shfl_xor(sa, m, 64);
        sb += __shfl_xor(sb, m, 64);
      }
      float ra = 1.f / sa, rb = 1.f / sb;
#pragma unroll
      for (int t = 0; t < 4; ++t) { sA[t][reg] *= ra; sB[t][reg] *= rb; }
    }
  }
  __syncthreads();  // B2.5: all K reads done; overlay M32 onto K region

  // ---- write M fp32 (msw swizzle; serves both PV and m-map path) ----
#pragma unroll
  for (int t = 0; t < 4; ++t)
#pragma unroll
    for (int reg = 0; reg < 4; ++reg) {
      int jrow = 16 * w + 4 * lg + reg, kcol = 16 * t + l15;
      M32A[msw(jrow, kcol)] = sA[t][reg];
      M32B[msw(jrow, kcol)] = sB[t][reg];
    }
  __syncthreads();  // B3: M complete

  // ---- PV via MFMA (fp16 cvt from fp32 M): X^T[c][j] = sum_k V_sel[k][c] * M[j][k] ----
  f32x4 pL[4], pR[4];
#pragma unroll
  for (int t = 0; t < 4; ++t) { pL[t] = (f32x4){0.f, 0.f, 0.f, 0.f}; pR[t] = pL[t]; }
#pragma unroll
  for (int h = 0; h < 2; ++h) {
    f16x8 va = __builtin_bit_cast(f16x8, vAr[h]);
    f16x8 vb = __builtin_bit_cast(f16x8, vBr[h]);
#pragma unroll
    for (int jt = 0; jt < 4; ++jt) {
      const float* mra = M32A + msw(16 * jt + l15, 32 * h + 8 * lg);
      const float* mrb = M32B + msw(16 * jt + l15, 32 * h + 8 * lg);
      float fa[8], fb[8];
      *(float4*)&fa[0] = *(const float4*)mra;
      *(float4*)&fa[4] = *(const float4*)(mra + 4);
      *(float4*)&fb[0] = *(const float4*)mrb;
      *(float4*)&fb[4] = *(const float4*)(mrb + 4);
      f16x8 ma, mb;
#pragma unroll
      for (int e = 0; e < 8; ++e) { ma[e] = (_Float16)fa[e]; mb[e] = (_Float16)fb[e]; }
      pL[jt] = __builtin_amdgcn_mfma_f32_16x16x32_f16(va, ma, pL[jt], 0, 0, 0);
      pR[jt] = __builtin_amdgcn_mfma_f32_16x16x32_f16(vb, mb, pR[jt], 0, 0, 0);
    }
  }
  // ---- x blend prefetch (T14): issue loads before m_relax, use after B4 ----
  float xlv[4][4], xrv[4][4];
#pragma unroll
  for (int jt = 0; jt < 4; ++jt)
#pragma unroll
    for (int reg = 0; reg < 4; ++reg) {
      int c = 16 * w + 4 * lg + reg;
      int j = 16 * jt + l15;
      int hp2 = hb * 8 + (j >> 3), wp2 = wb * 8 + (j & 7);
      size_t off = ((size_t)(b * 64 + c)) * HW + hp2 * 512 + wp2;
      xlv[jt][reg] = xL[off];
      xrv[jt][reg] = xR[off];
    }
  // ---- m_relax band + einsum + tanh from fp32 M (128 threads) ----
  if (tid < 128) {
    int dir = tid >> 6, j = tid & 63;
    const float* Mrow = dir ? M32B : M32A;
    const float* Mcol = dir ? M32A : M32B;
    float acc = 0.f;
    for (int k = 0; k < 64; ++k) {
      float rx = 0.f;
#pragma unroll
      for (int i = -2; i <= 2; ++i) {
        int jj = j + i;
        if ((unsigned)jj < 64u) rx += Mrow[msw(jj, k)];
      }
      acc += rx * Mcol[msw(k, j)];
    }
    (dir ? mapR : mapL)[j] = tanhf(5.f * acc);
  }
  __syncthreads();  // B4: maps ready

  // ---- blend + store ----
#pragma unroll
  for (int jt = 0; jt < 4; ++jt) {
#pragma unroll
    for (int reg = 0; reg < 4; ++reg) {
      int c = 16 * w + 4 * lg + reg;
      int j = 16 * jt + l15;
      int hp2 = hb * 8 + (j >> 3), wp2 = wb * 8 + (j & 7);
      size_t off = ((size_t)(b * 64 + c)) * HW + hp2 * 512 + wp2;
      float ml = mapL[j], mr = mapR[j];
      outL[off] = xlv[jt][reg] * (1.f - ml) + pL[jt][reg] * ml;
      outR[off] = xrv[jt][reg] * (1.f - mr) + pR[jt][reg] * mr;
    }
  }
}

extern "C" void kernel_launch(void* const* d_in, const int* in_sizes, int n_in,
                              void* d_out, int out_size, void* d_ws, size_t ws_size,
                              hipStream_t stream) {
  const float* x_left = (const float*)d_in[0];
  const float* x_right = (const float*)d_in[1];
  const float* d_left = (const float*)d_in[2];
  const float* d_right = (const float*)d_in[3];
  const float* bn_gamma = (const float*)d_in[4];
  const float* bn_beta = (const float*)d_in[5];
  const float* rb_w1 = (const float*)d_in[6];
  const float* rb_b1 = (const float*)d_in[7];
  const float* rb_w2 = (const float*)d_in[8];
  const float* rb_b2 = (const float*)d_in[9];
  const float* qkv_w = (const float*)d_in[10];
  const float* qkv_b = (const float*)d_in[11];

  float* ws = (float*)d_ws;
  const size_t S = S_ELEMS;
  unsigned short* tL = (unsigned short*)ws;              // S ushorts (conv1 out fp16)
  unsigned short* tR = tL + S;                           // S ushorts (ends at ws+S floats)
  float* knL = ws + 2 * S;           // S floats NHWC [b*HW+p][64]
  float* knR = ws + 3 * S;           // S floats
  unsigned short* vnL = (unsigned short*)(ws + 4 * S);   // S ushorts NHWC
  unsigned short* vnR = vnL + S;                         // S ushorts
  float* qnL = ws + 5 * S;           // S floats NHWC
  float* qnR = ws + 6 * S;           // S floats

  // partial/stats at head of d_out: written by bn kernels, read by conv kernels,
  // overwritten by attn's blend at the end (stream order guarantees safety).
  float* out_left = (float*)d_out;
  float* out_right = out_left + S;
  float2* partial = (float2*)d_out;              // 2048 float2
  float* stats = (float*)d_out + 4096;           // 256 floats

  bn_part_k<<<2048, 256, 0, stream>>>(x_left, x_right, partial);
  bn_fin_k<<<1, 128, 0, stream>>>(partial, bn_gamma, bn_beta, stats);

  conv1_k<<<8192, 256, 0, stream>>>(x_left, x_right, rb_w1, rb_b1, stats, tL, tR);
  conv2_qkv_k<<<8192, 256, 0, stream>>>(tL, tR, x_left, x_right, rb_w2, rb_b2,
                                        qkv_w, qkv_b, stats,
                                        qnL, qnR, knL, knR, vnL, vnR);
  attn_k<<<4096, 256, 0, stream>>>(qnL, qnR, knL, knR, vnL, vnR,
                                   d_left, d_right, x_left, x_right,
                                   out_left, out_right);
}

// Round 18
// 750.481 us; speedup vs baseline: 1.6103x; 1.6103x over previous
//
#include <hip/hip_runtime.h>
#include <cstdint>

#define HW 131072        // H*W
#define S_ELEMS 16777216 // B*C*H*W

typedef __attribute__((ext_vector_type(8))) _Float16 f16x8;
typedef __attribute__((ext_vector_type(4))) _Float16 f16x4;
typedef __attribute__((ext_vector_type(4))) float f32x4;

__device__ __forceinline__ float h2f(unsigned short u) {
  return (float)__builtin_bit_cast(_Float16, u);
}
__device__ __forceinline__ unsigned short f2h(float f) {
  return __builtin_bit_cast(unsigned short, (_Float16)f);
}
// M32 bank swizzle: XOR col 8-blocks by row-class; kills j/j+8/j+16/j+24 bank aliasing
// while keeping 8-float blocks contiguous (float4-aligned reads still valid).
__device__ __forceinline__ int msw(int r, int c) {
  return r * 68 + (c ^ (((r >> 3) & 3) << 3));
}

// ---------------- BN stats stage 1: partial sums (2 sides x 64 c x 16 slabs) ----------------
__global__ __launch_bounds__(256) void bn_part_k(const float* __restrict__ xL,
                                                 const float* __restrict__ xR,
                                                 float2* __restrict__ partial) {
  int bid = blockIdx.x;
  int side = bid >> 10, rest = bid & 1023;
  int c = rest >> 4, sl = rest & 15;
  const float* x = side ? xR : xL;
  const float4* p = (const float4*)(x + ((size_t)((sl >> 3) * 64 + c)) * HW + (size_t)(sl & 7) * 16384);
  float s1 = 0.f, s2 = 0.f;
  for (int i = threadIdx.x; i < 4096; i += 256) {
    float4 v = p[i];
    s1 += v.x + v.y + v.z + v.w;
    s2 += v.x * v.x + v.y * v.y + v.z * v.z + v.w * v.w;
  }
  for (int m = 32; m; m >>= 1) {
    s1 += __shfl_xor(s1, m, 64);
    s2 += __shfl_xor(s2, m, 64);
  }
  __shared__ float r1[4], r2[4];
  int wv = threadIdx.x >> 6;
  if ((threadIdx.x & 63) == 0) { r1[wv] = s1; r2[wv] = s2; }
  __syncthreads();
  if (threadIdx.x == 0) {
    partial[bid] = make_float2(r1[0] + r1[1] + r1[2] + r1[3], r2[0] + r2[1] + r2[2] + r2[3]);
  }
}

// ---------------- BN stats stage 2: finalize scale/shift ----------------
__global__ __launch_bounds__(128) void bn_fin_k(const float2* __restrict__ partial,
                                                const float* __restrict__ gamma,
                                                const float* __restrict__ beta,
                                                float* __restrict__ stats) {
  int tid = threadIdx.x;  // 0..127: side*64 + c
  int side = tid >> 6, c = tid & 63;
  float s1 = 0.f, s2 = 0.f;
  const float2* p = partial + (side * 1024 + c * 16);
  for (int s = 0; s < 16; ++s) { float2 v = p[s]; s1 += v.x; s2 += v.y; }
  float mu = s1 / 262144.f;
  float var = s2 / 262144.f - mu * mu;
  float rs = rsqrtf(var + 1e-5f);
  float sc = rs * gamma[c];
  stats[side * 128 + c] = sc;
  stats[side * 128 + 64 + c] = beta[c] - mu * sc;
}

// ---------------- conv1: tiled grouped 3x3 (8x32 tile), BN-in + leaky, fp16 LDS + fp16 out --
// launch_bounds (256,4): (256,6) in round 17 capped VGPRs -> scratch spill -> 2.27GB writes.
__global__ __launch_bounds__(256, 4) void conv1_k(const float* __restrict__ xL,
                                                  const float* __restrict__ xR,
                                                  const float* __restrict__ wgt,
                                                  const float* __restrict__ bias,
                                                  const float* __restrict__ stats,
                                                  unsigned short* __restrict__ tL,
                                                  unsigned short* __restrict__ tR) {
  __shared__ __align__(16) unsigned short sInH[16 * 10 * 36];  // bn(x) fp16 (11.5KB)
  __shared__ __align__(16) float sW[16 * 16 * 3 * 4];  // [o][ci][kh] float4 {w0,w1,w2,pad}
  __shared__ float sSc[16], sSh[16];
  int bid = blockIdx.x;
  int side = bid >> 12, rest = bid & 4095;
  int tw = rest & 15, th = (rest >> 4) & 31, g = (rest >> 9) & 3, b = rest >> 11;
  const float* in = side ? xR : xL;
  unsigned short* out = side ? tR : tL;
  const float* ss = stats + side * 128;
  int tid = threadIdx.x;
  for (int e = tid; e < 2304; e += 256) {
    int o = e / 144, rem = e - o * 144, ci = rem / 9, k = rem - ci * 9;
    sW[((o * 16 + ci) * 3 + k / 3) * 4 + k % 3] = wgt[(g * 16 + o) * 144 + rem];
  }
  if (tid < 16) { sSc[tid] = ss[g * 16 + tid]; sSh[tid] = ss[64 + g * 16 + tid]; }
  __syncthreads();  // RACE FIX: sSc/sSh visible before staging reads
  int h0 = th * 8 - 1, w0 = tw * 32 - 1;
  const float* inb = in + ((size_t)(b * 64 + g * 16)) * HW;
  for (int e = tid; e < 5440; e += 256) {
    int ci = e / 340, rem = e - ci * 340, r = rem / 34, c = rem - r * 34;
    int h = h0 + r, w = w0 + c;
    unsigned short v = 0;
    if ((unsigned)h < 256u && (unsigned)w < 512u) {
      v = f2h(inb[(size_t)ci * HW + h * 512 + w] * sSc[ci] + sSh[ci]);
    }
    sInH[ci * 360 + r * 36 + c] = v;
  }
  __syncthreads();
  int oh = tid >> 6;  // 0..3 output-channel quad
  int pxi = tid & 63;
  int row = pxi >> 3, col = (pxi & 7) * 4;
  float acc[4][4];
#pragma unroll
  for (int o = 0; o < 4; ++o) {
    float bz = bias[g * 16 + oh * 4 + o];
#pragma unroll
    for (int p = 0; p < 4; ++p) acc[o][p] = bz;
  }
  for (int ci = 0; ci < 16; ++ci) {
    float v[3][6];
    const unsigned short* base = sInH + ci * 360 + row * 36 + col;
#pragma unroll
    for (int kh = 0; kh < 3; ++kh) {
      ushort4 u0 = *(const ushort4*)(base + kh * 36);
      ushort2 u1 = *(const ushort2*)(base + kh * 36 + 4);
      v[kh][0] = h2f(u0.x); v[kh][1] = h2f(u0.y); v[kh][2] = h2f(u0.z);
      v[kh][3] = h2f(u0.w); v[kh][4] = h2f(u1.x); v[kh][5] = h2f(u1.y);
    }
    const float4* wb = (const float4*)sW + ((oh * 4) * 16 + ci) * 3;
#pragma unroll
    for (int o = 0; o < 4; ++o) {
      const float4* wo = wb + o * 48;
#pragma unroll
      for (int kh = 0; kh < 3; ++kh) {
        float4 wv = wo[kh];
#pragma unroll
        for (int p = 0; p < 4; ++p)
          acc[o][p] += wv.x * v[kh][p] + wv.y * v[kh][p + 1] + wv.z * v[kh][p + 2];
      }
    }
  }
  int h = th * 8 + row, wcol = tw * 32 + col;
#pragma unroll
  for (int o = 0; o < 4; ++o) {
    int cg = g * 16 + oh * 4 + o;
    size_t off = ((size_t)(b * 64 + cg)) * HW + h * 512 + wcol;
    ushort4 r4;
#pragma unroll
    for (int p = 0; p < 4; ++p) {
      float a = acc[o][p];
      a = a > 0.f ? a : 0.1f * a;
      ((unsigned short*)&r4)[p] = f2h(a);
    }
    *(ushort4*)(out + off) = r4;
  }
}

// ---------------- fused conv2 + residual + qkv(MFMA); both sides ----------------
// LDS: sBuf unions {fp16 conv1-out tile [16][10][36] (11.5KB)} then {fp32 sR[16][260] (16.6KB)}
__global__ __launch_bounds__(256, 4) void conv2_qkv_k(
    const unsigned short* __restrict__ tL, const unsigned short* __restrict__ tR,
    const float* __restrict__ xL, const float* __restrict__ xR,
    const float* __restrict__ w2g, const float* __restrict__ b2g,
    const float* __restrict__ wq, const float* __restrict__ bq,
    const float* __restrict__ stats,
    float* __restrict__ qnL, float* __restrict__ qnR,
    float* __restrict__ knL, float* __restrict__ knR,
    unsigned short* __restrict__ vnL, unsigned short* __restrict__ vnR) {
  __shared__ __align__(16) float sBuf[4160];         // 16.6KB union
  __shared__ __align__(16) float sW2[16 * 16 * 3 * 4];
  __shared__ __align__(16) float sWq[768];
  __shared__ float sB2[16], sBq[48], sSc[16], sSh[16];
  unsigned short* sInH = (unsigned short*)sBuf;      // [16][10][36] fp16
  float* sR = sBuf;                                  // [16][260] fp32 (after conv2)

  int bid = blockIdx.x;
  int side = bid >> 12, rest = bid & 4095;
  int tw = rest & 15, th = (rest >> 4) & 31, g = (rest >> 9) & 3, b = rest >> 11;
  const unsigned short* t = side ? tR : tL;
  const float* x = side ? xR : xL;
  float* qn = side ? qnR : qnL;
  float* kn = side ? knR : knL;
  unsigned short* vn = side ? vnR : vnL;
  const float* ss = stats + side * 128;
  int tid = threadIdx.x;

  // early residual prefetch (T14): hide HBM latency under stage + conv2
  int oh = tid >> 6;
  int pxi = tid & 63;
  int row = pxi >> 3, col = (pxi & 7) * 4;
  float4 resx[4];
  {
    int h = th * 8 + row, wcol = tw * 32 + col;
#pragma unroll
    for (int o = 0; o < 4; ++o) {
      int cg = g * 16 + oh * 4 + o;
      resx[o] = *(const float4*)(x + ((size_t)(b * 64 + cg)) * HW + h * 512 + wcol);
    }
  }

  for (int e = tid; e < 2304; e += 256) {
    int o = e / 144, rem = e - o * 144, ci = rem / 9, k = rem - ci * 9;
    sW2[((o * 16 + ci) * 3 + k / 3) * 4 + k % 3] = w2g[(g * 16 + o) * 144 + rem];
  }
  for (int e = tid; e < 768; e += 256) {
    int oo = e >> 4, ci = e & 15;
    sWq[e] = wq[(g * 48 + oo) * 16 + ci];
  }
  if (tid < 48) sBq[tid] = bq[g * 48 + tid];
  if (tid < 16) {
    sB2[tid] = b2g[g * 16 + tid];
    sSc[tid] = ss[g * 16 + tid];
    sSh[tid] = ss[64 + g * 16 + tid];
  }
  __syncthreads();  // LDS scalars visible before any use (race-fix discipline)

  // ---- stage conv1-out tile (1-halo) from global fp16 -> LDS fp16 ----
  int h0 = th * 8 - 1, w0 = tw * 32 - 1;
  const unsigned short* inb = t + ((size_t)(b * 64 + g * 16)) * HW;
  for (int e = tid; e < 5440; e += 256) {
    int ci = e / 340, rem = e - ci * 340, r = rem / 34, c = rem - r * 34;
    int h = h0 + r, w = w0 + c;
    unsigned short v = 0;
    if ((unsigned)h < 256u && (unsigned)w < 512u) {
      v = inb[(size_t)ci * HW + h * 512 + w];
    }
    sInH[ci * 360 + r * 36 + c] = v;
  }
  __syncthreads();

  // ---- conv2 (4 oc per thread, fp16 LDS reads) + residual ----
  float acc[4][4];
#pragma unroll
  for (int o = 0; o < 4; ++o) {
    float bz = sB2[oh * 4 + o];
#pragma unroll
    for (int p = 0; p < 4; ++p) acc[o][p] = bz;
  }
  for (int ci = 0; ci < 16; ++ci) {
    float v[3][6];
    const unsigned short* base = sInH + ci * 360 + row * 36 + col;
#pragma unroll
    for (int kh = 0; kh < 3; ++kh) {
      ushort4 u0 = *(const ushort4*)(base + kh * 36);
      ushort2 u1 = *(const ushort2*)(base + kh * 36 + 4);
      v[kh][0] = h2f(u0.x); v[kh][1] = h2f(u0.y); v[kh][2] = h2f(u0.z);
      v[kh][3] = h2f(u0.w); v[kh][4] = h2f(u1.x); v[kh][5] = h2f(u1.y);
    }
    const float4* wb = (const float4*)sW2 + ((oh * 4) * 16 + ci) * 3;
#pragma unroll
    for (int o = 0; o < 4; ++o) {
      const float4* wo = wb + o * 48;
#pragma unroll
      for (int kh = 0; kh < 3; ++kh) {
        float4 wv = wo[kh];
#pragma unroll
        for (int p = 0; p < 4; ++p)
          acc[o][p] += wv.x * v[kh][p] + wv.y * v[kh][p + 1] + wv.z * v[kh][p + 2];
      }
    }
  }
#pragma unroll
  for (int o = 0; o < 4; ++o) {
    float sc = sSc[oh * 4 + o], sh = sSh[oh * 4 + o];
#pragma unroll
    for (int p = 0; p < 4; ++p) acc[o][p] += ((float*)&resx[o])[p] * sc + sh;
  }
  __syncthreads();  // all sInH reads done; safe to overlay sR

  // ---- write r-tile into sR[16][260] ----
#pragma unroll
  for (int o = 0; o < 4; ++o) {
    float* dst = sR + (oh * 4 + o) * 260 + row * 32 + col;
#pragma unroll
    for (int p = 0; p < 4; ++p) dst[p] = acc[o][p];
  }
  __syncthreads();

  // ---- qkv via split-fp16 MFMA: O[48][256] = W[48][16] . r[16][256] ----
  {
    const int lane = tid & 63, wv = tid >> 6;
    const int l15 = lane & 15, lg = lane >> 4;
    f16x4 WH[3], WL[3];
#pragma unroll
    for (int rt = 0; rt < 3; ++rt) {
      float4 wvv = *(const float4*)(sWq + (rt * 16 + l15) * 16 + 4 * lg);
#pragma unroll
      for (int i = 0; i < 4; ++i) {
        float f = ((float*)&wvv)[i];
        _Float16 h = (_Float16)f;
        WH[rt][i] = h;
        WL[rt][i] = (_Float16)(f - (float)h);
      }
    }
#pragma unroll
    for (int j = 0; j < 4; ++j) {
      int ct = 4 * wv + j;
      f16x4 rh, rl;
#pragma unroll
      for (int i = 0; i < 4; ++i) {
        float f = sR[(4 * lg + i) * 260 + ct * 16 + l15];
        _Float16 h = (_Float16)f;
        rh[i] = h;
        rl[i] = (_Float16)(f - (float)h);
      }
      int px = ct * 16 + l15;
      int hpix = th * 8 + (px >> 5), wpix = tw * 32 + (px & 31);
      size_t pxbase = ((size_t)b * HW + hpix * 512 + wpix) * 64;
#pragma unroll
      for (int rt = 0; rt < 3; ++rt) {
        f32x4 a;
#pragma unroll
        for (int r = 0; r < 4; ++r) a[r] = sBq[rt * 16 + 4 * lg + r];
        a = __builtin_amdgcn_mfma_f32_16x16x16f16(WH[rt], rh, a, 0, 0, 0);
        a = __builtin_amdgcn_mfma_f32_16x16x16f16(WH[rt], rl, a, 0, 0, 0);
        a = __builtin_amdgcn_mfma_f32_16x16x16f16(WL[rt], rh, a, 0, 0, 0);
        int ob = g * 48 + rt * 16 + 4 * lg;
        if (ob < 64) {
          *(float4*)(qn + pxbase + ob) = *(float4*)&a;
        } else if (ob < 128) {
          *(float4*)(kn + pxbase + (ob - 64)) = *(float4*)&a;
        } else {
          uint2 pk;
          pk.x = (uint32_t)f2h(a[0]) | ((uint32_t)f2h(a[1]) << 16);
          pk.y = (uint32_t)f2h(a[2]) | ((uint32_t)f2h(a[3]) << 16);
          *(uint2*)(vn + pxbase + (ob - 128)) = pk;
        }
      }
    }
  }
}

// ---------------- fused per-window attention: split-fp16 MFMA, all-NHWC, XCD swizzle ----
__global__ __launch_bounds__(256, 4) void attn_k(
    const float* __restrict__ qLn, const float* __restrict__ qRn,  // NHWC fp32
    const float* __restrict__ kLn, const float* __restrict__ kRn,  // NHWC fp32
    const unsigned short* __restrict__ vLn, const unsigned short* __restrict__ vRn, // NHWC fp16
    const float* __restrict__ dL, const float* __restrict__ dR,
    const float* __restrict__ xL, const float* __restrict__ xR,
    float* outL, float* outR) {
  // XCD-aware swizzle: consecutive windows -> same XCD L2 (4096 % 8 == 0, bijective)
  const int orig = blockIdx.x;
  const int n = (orig & 7) * 512 + (orig >> 3);
  const int b = n >> 11, hb = (n >> 6) & 31, wb = n & 63;
  const int tid = threadIdx.x;
  const int lane = tid & 63, w = tid >> 6;
  const int l15 = lane & 15, lg = lane >> 4;

  // K hi/lo (stride 72, fp16) — region reused after QK^T as fp32 M (stride 68, msw-swizzled)
  __shared__ __align__(16) unsigned short sK[4 * 64 * 72];   // 36864 B
  __shared__ float meanA[8], meanB[8], qsA[64], qsB[64], mapL[64], mapR[64];
  unsigned short* KHA = sK;
  unsigned short* KLA = sK + 64 * 72;
  unsigned short* KHB = sK + 2 * 64 * 72;
  unsigned short* KLB = sK + 3 * 64 * 72;
  float* M32A = (float*)sK;           // [64][68] msw layout
  float* M32B = (float*)sK + 64 * 68; // [64][68]

  const float* dLb = dL + (size_t)b * HW;
  const float* dRb = dR + (size_t)b * HW;
  const size_t nb = (size_t)b * HW;

  // ---- K gather (NHWC): 2 iters, 8 channels per thread per dir ----
  const int cc0 = (wb & 7) * 8;
#pragma unroll
  for (int it = 0; it < 2; ++it) {
    int slot = tid + 256 * it;           // 0..511
    int c2 = slot & 63, k8 = slot >> 6;  // k8 0..7
    int hh = 4 * c2 + (hb >> 3);
    int ww = (hb & 7) * 64 + k8 * 8 + (wb >> 3);
    int dpos = hh * 512 + ww;
    int iwr = ww - (int)dLb[dpos]; iwr = min(max(iwr, 0), 511);
    int iwl = ww + (int)dRb[dpos]; iwl = min(max(iwl, 0), 511);
    const float* pr = kRn + (nb + hh * 512 + iwr) * 64 + cc0;
    const float* pl = kLn + (nb + hh * 512 + iwl) * 64 + cc0;
    float fr[8], fl[8];
    *(float4*)&fr[0] = *(const float4*)pr;
    *(float4*)&fr[4] = *(const float4*)(pr + 4);
    *(float4*)&fl[0] = *(const float4*)pl;
    *(float4*)&fl[4] = *(const float4*)(pl + 4);
#pragma unroll
    for (int kl = 0; kl < 8; ++kl) {
      int k = 8 * k8 + kl;
      unsigned short hr = f2h(fr[kl]), hl = f2h(fl[kl]);
      KHA[k * 72 + c2] = hr; KLA[k * 72 + c2] = f2h(fr[kl] - h2f(hr));
      KHB[k * 72 + c2] = hl; KLB[k * 72 + c2] = f2h(fl[kl] - h2f(hl));
    }
  }

  // ---- Q load (NHWC fp32) + hi/lo split ----
  const int jr = 16 * w + l15;
  const int hp = hb * 8 + (jr >> 3), wp = wb * 8 + (jr & 7);
  const int gpix = hp * 512 + wp;
  const float* qlp = qLn + (nb + gpix) * 64;
  const float* qrp = qRn + (nb + gpix) * 64;
  float qv0[8], qv1[8], qw0[8], qw1[8];
  *(float4*)&qv0[0] = *(const float4*)(qlp + 8 * lg);
  *(float4*)&qv0[4] = *(const float4*)(qlp + 8 * lg + 4);
  *(float4*)&qv1[0] = *(const float4*)(qlp + 32 + 8 * lg);
  *(float4*)&qv1[4] = *(const float4*)(qlp + 32 + 8 * lg + 4);
  *(float4*)&qw0[0] = *(const float4*)(qrp + 8 * lg);
  *(float4*)&qw0[4] = *(const float4*)(qrp + 8 * lg + 4);
  *(float4*)&qw1[0] = *(const float4*)(qrp + 32 + 8 * lg);
  *(float4*)&qw1[4] = *(const float4*)(qrp + 32 + 8 * lg + 4);
  f16x8 qah0, qal0, qah1, qal1, qbh0, qbl0, qbh1, qbl1;
#pragma unroll
  for (int e = 0; e < 8; ++e) {
    _Float16 h;
    h = (_Float16)qv0[e]; qah0[e] = h; qal0[e] = (_Float16)(qv0[e] - (float)h);
    h = (_Float16)qv1[e]; qah1[e] = h; qal1[e] = (_Float16)(qv1[e] - (float)h);
    h = (_Float16)qw0[e]; qbh0[e] = h; qbl0[e] = (_Float16)(qw0[e] - (float)h);
    h = (_Float16)qw1[e]; qbh1[e] = h; qbl1[e] = (_Float16)(qw1[e] - (float)h);
  }

  // ---- V fragments (NHWC fp16: one b128 per (h,dir)) ----
  int4 vAr[2], vBr[2];
  {
    const int cv = 16 * w + l15;
#pragma unroll
    for (int h = 0; h < 2; ++h) {
      int hi = 4 * h + lg;
      int hh = 4 * cv + (hb >> 3);
      int ww = (hb & 7) * 64 + hi * 8 + (wb >> 3);
      int dpos = hh * 512 + ww;
      int iwr = ww - (int)dLb[dpos]; iwr = min(max(iwr, 0), 511);
      int iwl = ww + (int)dRb[dpos]; iwl = min(max(iwl, 0), 511);
      vAr[h] = *(const int4*)(vRn + (nb + hh * 512 + iwr) * 64 + cc0);
      vBr[h] = *(const int4*)(vLn + (nb + hh * 512 + iwl) * 64 + cc0);
    }
  }
  __syncthreads();  // B1: K staged

  // ---- K means per (dir,hi) over (wi,c): exact = hi+lo ----
  {
    int grp = tid >> 4, i = tid & 15;
    int dir = grp >> 3, hi = grp & 7;
    int off0 = (8 * hi + (i >> 1)) * 72 + (i & 1) * 32;
    const unsigned short* srcH = (dir ? KHB : KHA) + off0;
    const unsigned short* srcL = (dir ? KLB : KLA) + off0;
    float s = 0.f;
#pragma unroll
    for (int q = 0; q < 32; ++q) s += h2f(srcH[q]) + h2f(srcL[q]);
    for (int m = 8; m; m >>= 1) s += __shfl_xor(s, m, 64);
    if (i == 0) (dir ? meanB : meanA)[hi] = s * (1.f / 512.f);
  }
  // ---- qsum[j] (fp32 exact) ----
  {
    float sa = 0.f, sb = 0.f;
#pragma unroll
    for (int e = 0; e < 8; ++e) {
      sa += qv0[e] + qv1[e];
      sb += qw0[e] + qw1[e];
    }
    sa += __shfl_xor(sa, 16, 64); sa += __shfl_xor(sa, 32, 64);
    sb += __shfl_xor(sb, 16, 64); sb += __shfl_xor(sb, 32, 64);
    if (lane < 16) { qsA[jr] = sa; qsB[jr] = sb; }
  }
  __syncthreads();  // B2: means + qsums ready

  // ---- QK^T via split-fp16 MFMA: q.k ~= qh.kh + qh.kl + ql.kh ----
  f32x4 sA[4], sB[4];
#pragma unroll
  for (int t = 0; t < 4; ++t) { sA[t] = (f32x4){0.f, 0.f, 0.f, 0.f}; sB[t] = sA[t]; }
#pragma unroll
  for (int t = 0; t < 4; ++t) {
    int ro = (16 * t + l15) * 72 + 8 * lg;
    f16x8 kh0 = *(const f16x8*)(KHA + ro);
    f16x8 kl0 = *(const f16x8*)(KLA + ro);
    f16x8 kh1 = *(const f16x8*)(KHA + ro + 32);
    f16x8 kl1 = *(const f16x8*)(KLA + ro + 32);
    sA[t] = __builtin_amdgcn_mfma_f32_16x16x32_f16(qah0, kh0, sA[t], 0, 0, 0);
    sA[t] = __builtin_amdgcn_mfma_f32_16x16x32_f16(qah0, kl0, sA[t], 0, 0, 0);
    sA[t] = __builtin_amdgcn_mfma_f32_16x16x32_f16(qal0, kh0, sA[t], 0, 0, 0);
    sA[t] = __builtin_amdgcn_mfma_f32_16x16x32_f16(qah1, kh1, sA[t], 0, 0, 0);
    sA[t] = __builtin_amdgcn_mfma_f32_16x16x32_f16(qah1, kl1, sA[t], 0, 0, 0);
    sA[t] = __builtin_amdgcn_mfma_f32_16x16x32_f16(qal1, kh1, sA[t], 0, 0, 0);
    f16x8 mh0 = *(const f16x8*)(KHB + ro);
    f16x8 ml0 = *(const f16x8*)(KLB + ro);
    f16x8 mh1 = *(const f16x8*)(KHB + ro + 32);
    f16x8 ml1 = *(const f16x8*)(KLB + ro + 32);
    sB[t] = __builtin_amdgcn_mfma_f32_16x16x32_f16(qbh0, mh0, sB[t], 0, 0, 0);
    sB[t] = __builtin_amdgcn_mfma_f32_16x16x32_f16(qbh0, ml0, sB[t], 0, 0, 0);
    sB[t] = __builtin_amdgcn_mfma_f32_16x16x32_f16(qbl0, mh0, sB[t], 0, 0, 0);
    sB[t] = __builtin_amdgcn_mfma_f32_16x16x32_f16(qbh1, mh1, sB[t], 0, 0, 0);
    sB[t] = __builtin_amdgcn_mfma_f32_16x16x32_f16(qbh1, ml1, sB[t], 0, 0, 0);
    sB[t] = __builtin_amdgcn_mfma_f32_16x16x32_f16(qbl1, mh1, sB[t], 0, 0, 0);
  }
  // ---- mean-fold correction + in-register softmax over k ----
  {
    float qra[4], qrb2[4];
#pragma unroll
    for (int reg = 0; reg < 4; ++reg) {
      qra[reg] = qsA[16 * w + 4 * lg + reg];
      qrb2[reg] = qsB[16 * w + 4 * lg + reg];
    }
#pragma unroll
    for (int t = 0; t < 4; ++t) {
      float mA_ = meanA[2 * t + (l15 >> 3)];
      float mB_ = meanB[2 * t + (l15 >> 3)];
#pragma unroll
      for (int reg = 0; reg < 4; ++reg) {
        sA[t][reg] -= qra[reg] * mA_;
        sB[t][reg] -= qrb2[reg] * mB_;
      }
    }
#pragma unroll
    for (int reg = 0; reg < 4; ++reg) {
      float ma = sA[0][reg], mb = sB[0][reg];
#pragma unroll
      for (int t = 1; t < 4; ++t) { ma = fmaxf(ma, sA[t][reg]); mb = fmaxf(mb, sB[t][reg]); }
#pragma unroll
      for (int m = 1; m <= 8; m <<= 1) {
        ma = fmaxf(ma, __shfl_xor(ma, m, 64));
        mb = fmaxf(mb, __shfl_xor(mb, m, 64));
      }
      float sa = 0.f, sb = 0.f;
#pragma unroll
      for (int t = 0; t < 4; ++t) {
        float ea = __expf(sA[t][reg] - ma), eb = __expf(sB[t][reg] - mb);
        sA[t][reg] = ea; sB[t][reg] = eb;
        sa += ea; sb += eb;
      }
#pragma unroll
      for (int m = 1; m <= 8; m <<= 1) {
        sa += __shfl_xor(sa, m, 64);
        sb += __shfl_xor(sb, m, 64);
      }
      float ra = 1.f / sa, rb = 1.f / sb;
#pragma unroll
      for (int t = 0; t < 4; ++t) { sA[t][reg] *= ra; sB[t][reg] *= rb; }
    }
  }
  __syncthreads();  // B2.5: all K reads done; overlay M32 onto K region

  // ---- write M fp32 (msw swizzle; serves both PV and m-map path) ----
#pragma unroll
  for (int t = 0; t < 4; ++t)
#pragma unroll
    for (int reg = 0; reg < 4; ++reg) {
      int jrow = 16 * w + 4 * lg + reg, kcol = 16 * t + l15;
      M32A[msw(jrow, kcol)] = sA[t][reg];
      M32B[msw(jrow, kcol)] = sB[t][reg];
    }
  __syncthreads();  // B3: M complete

  // ---- PV via MFMA (fp16 cvt from fp32 M): X^T[c][j] = sum_k V_sel[k][c] * M[j][k] ----
  f32x4 pL[4], pR[4];
#pragma unroll
  for (int t = 0; t < 4; ++t) { pL[t] = (f32x4){0.f, 0.f, 0.f, 0.f}; pR[t] = pL[t]; }
#pragma unroll
  for (int h = 0; h < 2; ++h) {
    f16x8 va = __builtin_bit_cast(f16x8, vAr[h]);
    f16x8 vb = __builtin_bit_cast(f16x8, vBr[h]);
#pragma unroll
    for (int jt = 0; jt < 4; ++jt) {
      const float* mra = M32A + msw(16 * jt + l15, 32 * h + 8 * lg);
      const float* mrb = M32B + msw(16 * jt + l15, 32 * h + 8 * lg);
      float fa[8], fb[8];
      *(float4*)&fa[0] = *(const float4*)mra;
      *(float4*)&fa[4] = *(const float4*)(mra + 4);
      *(float4*)&fb[0] = *(const float4*)mrb;
      *(float4*)&fb[4] = *(const float4*)(mrb + 4);
      f16x8 ma, mb;
#pragma unroll
      for (int e = 0; e < 8; ++e) { ma[e] = (_Float16)fa[e]; mb[e] = (_Float16)fb[e]; }
      pL[jt] = __builtin_amdgcn_mfma_f32_16x16x32_f16(va, ma, pL[jt], 0, 0, 0);
      pR[jt] = __builtin_amdgcn_mfma_f32_16x16x32_f16(vb, mb, pR[jt], 0, 0, 0);
    }
  }
  // ---- x blend prefetch (T14): issue loads before m_relax, use after B4 ----
  float xlv[4][4], xrv[4][4];
#pragma unroll
  for (int jt = 0; jt < 4; ++jt)
#pragma unroll
    for (int reg = 0; reg < 4; ++reg) {
      int c = 16 * w + 4 * lg + reg;
      int j = 16 * jt + l15;
      int hp2 = hb * 8 + (j >> 3), wp2 = wb * 8 + (j & 7);
      size_t off = ((size_t)(b * 64 + c)) * HW + hp2 * 512 + wp2;
      xlv[jt][reg] = xL[off];
      xrv[jt][reg] = xR[off];
    }
  // ---- m_relax band + einsum + tanh from fp32 M (128 threads) ----
  if (tid < 128) {
    int dir = tid >> 6, j = tid & 63;
    const float* Mrow = dir ? M32B : M32A;
    const float* Mcol = dir ? M32A : M32B;
    float acc = 0.f;
    for (int k = 0; k < 64; ++k) {
      float rx = 0.f;
#pragma unroll
      for (int i = -2; i <= 2; ++i) {
        int jj = j + i;
        if ((unsigned)jj < 64u) rx += Mrow[msw(jj, k)];
      }
      acc += rx * Mcol[msw(k, j)];
    }
    (dir ? mapR : mapL)[j] = tanhf(5.f * acc);
  }
  __syncthreads();  // B4: maps ready

  // ---- blend + store ----
#pragma unroll
  for (int jt = 0; jt < 4; ++jt) {
#pragma unroll
    for (int reg = 0; reg < 4; ++reg) {
      int c = 16 * w + 4 * lg + reg;
      int j = 16 * jt + l15;
      int hp2 = hb * 8 + (j >> 3), wp2 = wb * 8 + (j & 7);
      size_t off = ((size_t)(b * 64 + c)) * HW + hp2 * 512 + wp2;
      float ml = mapL[j], mr = mapR[j];
      outL[off] = xlv[jt][reg] * (1.f - ml) + pL[jt][reg] * ml;
      outR[off] = xrv[jt][reg] * (1.f - mr) + pR[jt][reg] * mr;
    }
  }
}

extern "C" void kernel_launch(void* const* d_in, const int* in_sizes, int n_in,
                              void* d_out, int out_size, void* d_ws, size_t ws_size,
                              hipStream_t stream) {
  const float* x_left = (const float*)d_in[0];
  const float* x_right = (const float*)d_in[1];
  const float* d_left = (const float*)d_in[2];
  const float* d_right = (const float*)d_in[3];
  const float* bn_gamma = (const float*)d_in[4];
  const float* bn_beta = (const float*)d_in[5];
  const float* rb_w1 = (const float*)d_in[6];
  const float* rb_b1 = (const float*)d_in[7];
  const float* rb_w2 = (const float*)d_in[8];
  const float* rb_b2 = (const float*)d_in[9];
  const float* qkv_w = (const float*)d_in[10];
  const float* qkv_b = (const float*)d_in[11];

  float* ws = (float*)d_ws;
  const size_t S = S_ELEMS;
  unsigned short* tL = (unsigned short*)ws;              // S ushorts (conv1 out fp16)
  unsigned short* tR = tL + S;                           // S ushorts (ends at ws+S floats)
  float* knL = ws + 2 * S;           // S floats NHWC [b*HW+p][64]
  float* knR = ws + 3 * S;           // S floats
  unsigned short* vnL = (unsigned short*)(ws + 4 * S);   // S ushorts NHWC
  unsigned short* vnR = vnL + S;                         // S ushorts
  float* qnL = ws + 5 * S;           // S floats NHWC
  float* qnR = ws + 6 * S;           // S floats

  // partial/stats at head of d_out: written by bn kernels, read by conv kernels,
  // overwritten by attn's blend at the end (stream order guarantees safety).
  float* out_left = (float*)d_out;
  float* out_right = out_left + S;
  float2* partial = (float2*)d_out;              // 2048 float2
  float* stats = (float*)d_out + 4096;           // 256 floats

  bn_part_k<<<2048, 256, 0, stream>>>(x_left, x_right, partial);
  bn_fin_k<<<1, 128, 0, stream>>>(partial, bn_gamma, bn_beta, stats);

  conv1_k<<<8192, 256, 0, stream>>>(x_left, x_right, rb_w1, rb_b1, stats, tL, tR);
  conv2_qkv_k<<<8192, 256, 0, stream>>>(tL, tR, x_left, x_right, rb_w2, rb_b2,
                                        qkv_w, qkv_b, stats,
                                        qnL, qnR, knL, knR, vnL, vnR);
  attn_k<<<4096, 256, 0, stream>>>(qnL, qnR, knL, knR, vnL, vnR,
                                   d_left, d_right, x_left, x_right,
                                   out_left, out_right);
}

// Round 19
// 704.183 us; speedup vs baseline: 1.7162x; 1.0657x over previous
//
#include <hip/hip_runtime.h>
#include <cstdint>

#define HW 131072        // H*W
#define S_ELEMS 16777216 // B*C*H*W

typedef __attribute__((ext_vector_type(8))) _Float16 f16x8;
typedef __attribute__((ext_vector_type(4))) _Float16 f16x4;
typedef __attribute__((ext_vector_type(4))) float f32x4;

__device__ __forceinline__ float h2f(unsigned short u) {
  return (float)__builtin_bit_cast(_Float16, u);
}
__device__ __forceinline__ unsigned short f2h(float f) {
  return __builtin_bit_cast(unsigned short, (_Float16)f);
}
// M32 bank swizzle: XOR col 8-blocks by row-class; kills j/j+8/j+16/j+24 bank aliasing
// while keeping 8-float blocks contiguous (float4-aligned reads still valid).
__device__ __forceinline__ int msw(int r, int c) {
  return r * 68 + (c ^ (((r >> 3) & 3) << 3));
}

// ---------------- BN stats stage 1: partial sums (2 sides x 64 c x 16 slabs) ----------------
__global__ __launch_bounds__(256) void bn_part_k(const float* __restrict__ xL,
                                                 const float* __restrict__ xR,
                                                 float2* __restrict__ partial) {
  int bid = blockIdx.x;
  int side = bid >> 10, rest = bid & 1023;
  int c = rest >> 4, sl = rest & 15;
  const float* x = side ? xR : xL;
  const float4* p = (const float4*)(x + ((size_t)((sl >> 3) * 64 + c)) * HW + (size_t)(sl & 7) * 16384);
  float s1 = 0.f, s2 = 0.f;
  for (int i = threadIdx.x; i < 4096; i += 256) {
    float4 v = p[i];
    s1 += v.x + v.y + v.z + v.w;
    s2 += v.x * v.x + v.y * v.y + v.z * v.z + v.w * v.w;
  }
  for (int m = 32; m; m >>= 1) {
    s1 += __shfl_xor(s1, m, 64);
    s2 += __shfl_xor(s2, m, 64);
  }
  __shared__ float r1[4], r2[4];
  int wv = threadIdx.x >> 6;
  if ((threadIdx.x & 63) == 0) { r1[wv] = s1; r2[wv] = s2; }
  __syncthreads();
  if (threadIdx.x == 0) {
    partial[bid] = make_float2(r1[0] + r1[1] + r1[2] + r1[3], r2[0] + r2[1] + r2[2] + r2[3]);
  }
}

// ---------------- BN stats stage 2: finalize scale/shift ----------------
__global__ __launch_bounds__(128) void bn_fin_k(const float2* __restrict__ partial,
                                                const float* __restrict__ gamma,
                                                const float* __restrict__ beta,
                                                float* __restrict__ stats) {
  int tid = threadIdx.x;  // 0..127: side*64 + c
  int side = tid >> 6, c = tid & 63;
  float s1 = 0.f, s2 = 0.f;
  const float2* p = partial + (side * 1024 + c * 16);
  for (int s = 0; s < 16; ++s) { float2 v = p[s]; s1 += v.x; s2 += v.y; }
  float mu = s1 / 262144.f;
  float var = s2 / 262144.f - mu * mu;
  float rs = rsqrtf(var + 1e-5f);
  float sc = rs * gamma[c];
  stats[side * 128 + c] = sc;
  stats[side * 128 + 64 + c] = beta[c] - mu * sc;
}

// ---------------- conv1: tiled grouped 3x3 (8x32 tile), BN-in + leaky, fp16 LDS + fp16 out --
// launch_bounds (256,4): (256,6) in round 17 capped VGPRs -> scratch spill -> 2.27GB writes.
__global__ __launch_bounds__(256, 4) void conv1_k(const float* __restrict__ xL,
                                                  const float* __restrict__ xR,
                                                  const float* __restrict__ wgt,
                                                  const float* __restrict__ bias,
                                                  const float* __restrict__ stats,
                                                  unsigned short* __restrict__ tL,
                                                  unsigned short* __restrict__ tR) {
  __shared__ __align__(16) unsigned short sInH[16 * 10 * 36];  // bn(x) fp16 (11.5KB)
  __shared__ __align__(16) float sW[16 * 16 * 3 * 4];  // [o][ci][kh] float4 {w0,w1,w2,pad}
  __shared__ float sSc[16], sSh[16];
  int bid = blockIdx.x;
  int side = bid >> 12, rest = bid & 4095;
  int tw = rest & 15, th = (rest >> 4) & 31, g = (rest >> 9) & 3, b = rest >> 11;
  const float* in = side ? xR : xL;
  unsigned short* out = side ? tR : tL;
  const float* ss = stats + side * 128;
  int tid = threadIdx.x;
  for (int e = tid; e < 2304; e += 256) {
    int o = e / 144, rem = e - o * 144, ci = rem / 9, k = rem - ci * 9;
    sW[((o * 16 + ci) * 3 + k / 3) * 4 + k % 3] = wgt[(g * 16 + o) * 144 + rem];
  }
  if (tid < 16) { sSc[tid] = ss[g * 16 + tid]; sSh[tid] = ss[64 + g * 16 + tid]; }
  __syncthreads();  // RACE FIX: sSc/sSh visible before staging reads
  int h0 = th * 8 - 1, w0 = tw * 32 - 1;
  const float* inb = in + ((size_t)(b * 64 + g * 16)) * HW;
  for (int e = tid; e < 5440; e += 256) {
    int ci = e / 340, rem = e - ci * 340, r = rem / 34, c = rem - r * 34;
    int h = h0 + r, w = w0 + c;
    unsigned short v = 0;
    if ((unsigned)h < 256u && (unsigned)w < 512u) {
      v = f2h(inb[(size_t)ci * HW + h * 512 + w] * sSc[ci] + sSh[ci]);
    }
    sInH[ci * 360 + r * 36 + c] = v;
  }
  __syncthreads();
  int oh = tid >> 6;  // 0..3 output-channel quad
  int pxi = tid & 63;
  int row = pxi >> 3, col = (pxi & 7) * 4;
  float acc[4][4];
#pragma unroll
  for (int o = 0; o < 4; ++o) {
    float bz = bias[g * 16 + oh * 4 + o];
#pragma unroll
    for (int p = 0; p < 4; ++p) acc[o][p] = bz;
  }
  for (int ci = 0; ci < 16; ++ci) {
    float v[3][6];
    const unsigned short* base = sInH + ci * 360 + row * 36 + col;
#pragma unroll
    for (int kh = 0; kh < 3; ++kh) {
      ushort4 u0 = *(const ushort4*)(base + kh * 36);
      ushort2 u1 = *(const ushort2*)(base + kh * 36 + 4);
      v[kh][0] = h2f(u0.x); v[kh][1] = h2f(u0.y); v[kh][2] = h2f(u0.z);
      v[kh][3] = h2f(u0.w); v[kh][4] = h2f(u1.x); v[kh][5] = h2f(u1.y);
    }
    const float4* wb = (const float4*)sW + ((oh * 4) * 16 + ci) * 3;
#pragma unroll
    for (int o = 0; o < 4; ++o) {
      const float4* wo = wb + o * 48;
#pragma unroll
      for (int kh = 0; kh < 3; ++kh) {
        float4 wv = wo[kh];
#pragma unroll
        for (int p = 0; p < 4; ++p)
          acc[o][p] += wv.x * v[kh][p] + wv.y * v[kh][p + 1] + wv.z * v[kh][p + 2];
      }
    }
  }
  int h = th * 8 + row, wcol = tw * 32 + col;
#pragma unroll
  for (int o = 0; o < 4; ++o) {
    int cg = g * 16 + oh * 4 + o;
    size_t off = ((size_t)(b * 64 + cg)) * HW + h * 512 + wcol;
    ushort4 r4;
#pragma unroll
    for (int p = 0; p < 4; ++p) {
      float a = acc[o][p];
      a = a > 0.f ? a : 0.1f * a;
      ((unsigned short*)&r4)[p] = f2h(a);
    }
    *(ushort4*)(out + off) = r4;
  }
}

// ---------------- fused conv2(MFMA implicit GEMM) + residual + qkv(MFMA); both sides --------
// conv2 = 9 taps of W_tap[16][16] . I_shift[16][256] via 16x16x16 MFMA.
// Chaining identity: conv2 D-frag (lane: oc=4lg+reg @ px=ct*16+l15) == qkv B-frag
// (lane: ci=4lg+i @ same px) -> accumulator feeds qkv directly, no LDS round trip.
__global__ __launch_bounds__(256) void conv2_qkv_k(
    const unsigned short* __restrict__ tL, const unsigned short* __restrict__ tR,
    const float* __restrict__ xL, const float* __restrict__ xR,
    const float* __restrict__ w2g, const float* __restrict__ b2g,
    const float* __restrict__ wq, const float* __restrict__ bq,
    const float* __restrict__ stats,
    float* __restrict__ qnL, float* __restrict__ qnR,
    float* __restrict__ knL, float* __restrict__ knR,
    unsigned short* __restrict__ vnL, unsigned short* __restrict__ vnR) {
  // ci-stride 372 ushorts: lg stride = 4*372/2 words = 744 % 32 = 8 -> full bank spread
  __shared__ __align__(16) unsigned short sInH[16 * 372];  // conv1-out fp16 tile +1 halo
  __shared__ __align__(16) float sW2r[2304];               // raw w2 [o][ci][9]
  __shared__ __align__(16) float sWq[768];
  __shared__ float sB2[16], sBq[48], sSc[16], sSh[16];

  int bid = blockIdx.x;
  int side = bid >> 12, rest = bid & 4095;
  int tw = rest & 15, th = (rest >> 4) & 31, g = (rest >> 9) & 3, b = rest >> 11;
  const unsigned short* t = side ? tR : tL;
  const float* x = side ? xR : xL;
  float* qn = side ? qnR : qnL;
  float* kn = side ? knR : knL;
  unsigned short* vn = side ? vnR : vnL;
  const float* ss = stats + side * 128;
  int tid = threadIdx.x;
  const int lane = tid & 63, wv = tid >> 6;
  const int l15 = lane & 15, lg = lane >> 4;

  // early residual prefetch (T14), in D layout: oc=4lg+r, px=ct*16+l15
  float resx[4][4];
#pragma unroll
  for (int j = 0; j < 4; ++j) {
    int px = (4 * wv + j) * 16 + l15;
    int hpix = th * 8 + (px >> 5), wpix = tw * 32 + (px & 31);
    size_t rowoff = (size_t)hpix * 512 + wpix;
#pragma unroll
    for (int r = 0; r < 4; ++r)
      resx[j][r] = x[((size_t)(b * 64 + g * 16 + 4 * lg + r)) * HW + rowoff];
  }

  // stage weights / biases / bn scale-shift
  for (int e = tid; e < 2304; e += 256) sW2r[e] = w2g[g * 2304 + e];
  for (int e = tid; e < 768; e += 256) {
    int oo = e >> 4, ci = e & 15;
    sWq[e] = wq[(g * 48 + oo) * 16 + ci];
  }
  if (tid < 48) sBq[tid] = bq[g * 48 + tid];
  if (tid < 16) {
    sB2[tid] = b2g[g * 16 + tid];
    sSc[tid] = ss[g * 16 + tid];
    sSh[tid] = ss[64 + g * 16 + tid];
  }

  // stage conv1-out tile (1-halo) from global fp16 -> LDS fp16 (padded stride)
  int h0 = th * 8 - 1, w0 = tw * 32 - 1;
  const unsigned short* inb = t + ((size_t)(b * 64 + g * 16)) * HW;
  for (int e = tid; e < 5440; e += 256) {
    int ci = e / 340, rem = e - ci * 340, r = rem / 34, c = rem - r * 34;
    int h = h0 + r, w = w0 + c;
    unsigned short v = 0;
    if ((unsigned)h < 256u && (unsigned)w < 512u) {
      v = inb[(size_t)ci * HW + h * 512 + w];
    }
    sInH[ci * 372 + r * 36 + c] = v;
  }
  __syncthreads();  // weights + tile staged (single barrier; nothing else writes LDS)

  // hoist A fragments: W2 taps (hi/lo split) + Wq (hi/lo)
  f16x4 W2H[9], W2L[9];
#pragma unroll
  for (int tap = 0; tap < 9; ++tap) {
#pragma unroll
    for (int i = 0; i < 4; ++i) {
      float f = sW2r[l15 * 144 + (4 * lg + i) * 9 + tap];
      _Float16 h = (_Float16)f;
      W2H[tap][i] = h;
      W2L[tap][i] = (_Float16)(f - (float)h);
    }
  }
  f16x4 WqH[3], WqL[3];
#pragma unroll
  for (int rt = 0; rt < 3; ++rt) {
    float4 wvv = *(const float4*)(sWq + (rt * 16 + l15) * 16 + 4 * lg);
#pragma unroll
    for (int i = 0; i < 4; ++i) {
      float f = ((float*)&wvv)[i];
      _Float16 h = (_Float16)f;
      WqH[rt][i] = h;
      WqL[rt][i] = (_Float16)(f - (float)h);
    }
  }
  float sc4[4], sh4[4], b24[4];
#pragma unroll
  for (int r = 0; r < 4; ++r) {
    sc4[r] = sSc[4 * lg + r];
    sh4[r] = sSh[4 * lg + r];
    b24[r] = sB2[4 * lg + r];
  }

  // per 16-px column block: conv2 MFMA -> residual -> split -> qkv MFMA -> store
#pragma unroll
  for (int j = 0; j < 4; ++j) {
    int ct = 4 * wv + j;
    int px = ct * 16 + l15;
    int prow = px >> 5, pcol = px & 31;
    const unsigned short* p0 = sInH + 0 * 372 + (4 * lg) * 372 + prow * 36 + pcol;
    f32x4 acc;
#pragma unroll
    for (int r = 0; r < 4; ++r) acc[r] = b24[r];
#pragma unroll
    for (int kh = 0; kh < 3; ++kh) {
#pragma unroll
      for (int kw = 0; kw < 3; ++kw) {
        int toff = kh * 36 + kw;
        f16x4 it;
#pragma unroll
        for (int i = 0; i < 4; ++i)
          it[i] = __builtin_bit_cast(_Float16, p0[i * 372 + toff]);
        acc = __builtin_amdgcn_mfma_f32_16x16x16f16(W2H[kh * 3 + kw], it, acc, 0, 0, 0);
        acc = __builtin_amdgcn_mfma_f32_16x16x16f16(W2L[kh * 3 + kw], it, acc, 0, 0, 0);
      }
    }
#pragma unroll
    for (int r = 0; r < 4; ++r) acc[r] += resx[j][r] * sc4[r] + sh4[r];
    // split r fragment (conv2 D == qkv B mapping: lane holds ci=4lg+i at px)
    f16x4 rh, rl;
#pragma unroll
    for (int i = 0; i < 4; ++i) {
      _Float16 h = (_Float16)acc[i];
      rh[i] = h;
      rl[i] = (_Float16)(acc[i] - (float)h);
    }
    int hpix = th * 8 + prow, wpix = tw * 32 + pcol;
    size_t pxbase = ((size_t)b * HW + hpix * 512 + wpix) * 64;
#pragma unroll
    for (int rt = 0; rt < 3; ++rt) {
      f32x4 a;
#pragma unroll
      for (int r = 0; r < 4; ++r) a[r] = sBq[rt * 16 + 4 * lg + r];
      a = __builtin_amdgcn_mfma_f32_16x16x16f16(WqH[rt], rh, a, 0, 0, 0);
      a = __builtin_amdgcn_mfma_f32_16x16x16f16(WqH[rt], rl, a, 0, 0, 0);
      a = __builtin_amdgcn_mfma_f32_16x16x16f16(WqL[rt], rh, a, 0, 0, 0);
      int ob = g * 48 + rt * 16 + 4 * lg;
      if (ob < 64) {
        *(float4*)(qn + pxbase + ob) = *(float4*)&a;
      } else if (ob < 128) {
        *(float4*)(kn + pxbase + (ob - 64)) = *(float4*)&a;
      } else {
        uint2 pk;
        pk.x = (uint32_t)f2h(a[0]) | ((uint32_t)f2h(a[1]) << 16);
        pk.y = (uint32_t)f2h(a[2]) | ((uint32_t)f2h(a[3]) << 16);
        *(uint2*)(vn + pxbase + (ob - 128)) = pk;
      }
    }
  }
}

// ---------------- fused per-window attention: split-fp16 MFMA, all-NHWC, XCD swizzle ----
__global__ __launch_bounds__(256, 4) void attn_k(
    const float* __restrict__ qLn, const float* __restrict__ qRn,  // NHWC fp32
    const float* __restrict__ kLn, const float* __restrict__ kRn,  // NHWC fp32
    const unsigned short* __restrict__ vLn, const unsigned short* __restrict__ vRn, // NHWC fp16
    const float* __restrict__ dL, const float* __restrict__ dR,
    const float* __restrict__ xL, const float* __restrict__ xR,
    float* outL, float* outR) {
  // XCD-aware swizzle: consecutive windows -> same XCD L2 (4096 % 8 == 0, bijective)
  const int orig = blockIdx.x;
  const int n = (orig & 7) * 512 + (orig >> 3);
  const int b = n >> 11, hb = (n >> 6) & 31, wb = n & 63;
  const int tid = threadIdx.x;
  const int lane = tid & 63, w = tid >> 6;
  const int l15 = lane & 15, lg = lane >> 4;

  // K hi/lo (stride 72, fp16) — region reused after QK^T as fp32 M (stride 68, msw-swizzled)
  __shared__ __align__(16) unsigned short sK[4 * 64 * 72];   // 36864 B
  __shared__ float meanA[8], meanB[8], qsA[64], qsB[64], mapL[64], mapR[64];
  unsigned short* KHA = sK;
  unsigned short* KLA = sK + 64 * 72;
  unsigned short* KHB = sK + 2 * 64 * 72;
  unsigned short* KLB = sK + 3 * 64 * 72;
  float* M32A = (float*)sK;           // [64][68] msw layout
  float* M32B = (float*)sK + 64 * 68; // [64][68]

  const float* dLb = dL + (size_t)b * HW;
  const float* dRb = dR + (size_t)b * HW;
  const size_t nb = (size_t)b * HW;

  // ---- K gather (NHWC): 2 iters, 8 channels per thread per dir ----
  const int cc0 = (wb & 7) * 8;
#pragma unroll
  for (int it = 0; it < 2; ++it) {
    int slot = tid + 256 * it;           // 0..511
    int c2 = slot & 63, k8 = slot >> 6;  // k8 0..7
    int hh = 4 * c2 + (hb >> 3);
    int ww = (hb & 7) * 64 + k8 * 8 + (wb >> 3);
    int dpos = hh * 512 + ww;
    int iwr = ww - (int)dLb[dpos]; iwr = min(max(iwr, 0), 511);
    int iwl = ww + (int)dRb[dpos]; iwl = min(max(iwl, 0), 511);
    const float* pr = kRn + (nb + hh * 512 + iwr) * 64 + cc0;
    const float* pl = kLn + (nb + hh * 512 + iwl) * 64 + cc0;
    float fr[8], fl[8];
    *(float4*)&fr[0] = *(const float4*)pr;
    *(float4*)&fr[4] = *(const float4*)(pr + 4);
    *(float4*)&fl[0] = *(const float4*)pl;
    *(float4*)&fl[4] = *(const float4*)(pl + 4);
#pragma unroll
    for (int kl = 0; kl < 8; ++kl) {
      int k = 8 * k8 + kl;
      unsigned short hr = f2h(fr[kl]), hl = f2h(fl[kl]);
      KHA[k * 72 + c2] = hr; KLA[k * 72 + c2] = f2h(fr[kl] - h2f(hr));
      KHB[k * 72 + c2] = hl; KLB[k * 72 + c2] = f2h(fl[kl] - h2f(hl));
    }
  }

  // ---- Q load (NHWC fp32) + hi/lo split ----
  const int jr = 16 * w + l15;
  const int hp = hb * 8 + (jr >> 3), wp = wb * 8 + (jr & 7);
  const int gpix = hp * 512 + wp;
  const float* qlp = qLn + (nb + gpix) * 64;
  const float* qrp = qRn + (nb + gpix) * 64;
  float qv0[8], qv1[8], qw0[8], qw1[8];
  *(float4*)&qv0[0] = *(const float4*)(qlp + 8 * lg);
  *(float4*)&qv0[4] = *(const float4*)(qlp + 8 * lg + 4);
  *(float4*)&qv1[0] = *(const float4*)(qlp + 32 + 8 * lg);
  *(float4*)&qv1[4] = *(const float4*)(qlp + 32 + 8 * lg + 4);
  *(float4*)&qw0[0] = *(const float4*)(qrp + 8 * lg);
  *(float4*)&qw0[4] = *(const float4*)(qrp + 8 * lg + 4);
  *(float4*)&qw1[0] = *(const float4*)(qrp + 32 + 8 * lg);
  *(float4*)&qw1[4] = *(const float4*)(qrp + 32 + 8 * lg + 4);
  f16x8 qah0, qal0, qah1, qal1, qbh0, qbl0, qbh1, qbl1;
#pragma unroll
  for (int e = 0; e < 8; ++e) {
    _Float16 h;
    h = (_Float16)qv0[e]; qah0[e] = h; qal0[e] = (_Float16)(qv0[e] - (float)h);
    h = (_Float16)qv1[e]; qah1[e] = h; qal1[e] = (_Float16)(qv1[e] - (float)h);
    h = (_Float16)qw0[e]; qbh0[e] = h; qbl0[e] = (_Float16)(qw0[e] - (float)h);
    h = (_Float16)qw1[e]; qbh1[e] = h; qbl1[e] = (_Float16)(qw1[e] - (float)h);
  }

  // ---- V fragments (NHWC fp16: one b128 per (h,dir)) ----
  int4 vAr[2], vBr[2];
  {
    const int cv = 16 * w + l15;
#pragma unroll
    for (int h = 0; h < 2; ++h) {
      int hi = 4 * h + lg;
      int hh = 4 * cv + (hb >> 3);
      int ww = (hb & 7) * 64 + hi * 8 + (wb >> 3);
      int dpos = hh * 512 + ww;
      int iwr = ww - (int)dLb[dpos]; iwr = min(max(iwr, 0), 511);
      int iwl = ww + (int)dRb[dpos]; iwl = min(max(iwl, 0), 511);
      vAr[h] = *(const int4*)(vRn + (nb + hh * 512 + iwr) * 64 + cc0);
      vBr[h] = *(const int4*)(vLn + (nb + hh * 512 + iwl) * 64 + cc0);
    }
  }
  __syncthreads();  // B1: K staged

  // ---- K means per (dir,hi) over (wi,c): exact = hi+lo ----
  {
    int grp = tid >> 4, i = tid & 15;
    int dir = grp >> 3, hi = grp & 7;
    int off0 = (8 * hi + (i >> 1)) * 72 + (i & 1) * 32;
    const unsigned short* srcH = (dir ? KHB : KHA) + off0;
    const unsigned short* srcL = (dir ? KLB : KLA) + off0;
    float s = 0.f;
#pragma unroll
    for (int q = 0; q < 32; ++q) s += h2f(srcH[q]) + h2f(srcL[q]);
    for (int m = 8; m; m >>= 1) s += __shfl_xor(s, m, 64);
    if (i == 0) (dir ? meanB : meanA)[hi] = s * (1.f / 512.f);
  }
  // ---- qsum[j] (fp32 exact) ----
  {
    float sa = 0.f, sb = 0.f;
#pragma unroll
    for (int e = 0; e < 8; ++e) {
      sa += qv0[e] + qv1[e];
      sb += qw0[e] + qw1[e];
    }
    sa += __shfl_xor(sa, 16, 64); sa += __shfl_xor(sa, 32, 64);
    sb += __shfl_xor(sb, 16, 64); sb += __shfl_xor(sb, 32, 64);
    if (lane < 16) { qsA[jr] = sa; qsB[jr] = sb; }
  }
  __syncthreads();  // B2: means + qsums ready

  // ---- QK^T via split-fp16 MFMA: q.k ~= qh.kh + qh.kl + ql.kh ----
  f32x4 sA[4], sB[4];
#pragma unroll
  for (int t = 0; t < 4; ++t) { sA[t] = (f32x4){0.f, 0.f, 0.f, 0.f}; sB[t] = sA[t]; }
#pragma unroll
  for (int t = 0; t < 4; ++t) {
    int ro = (16 * t + l15) * 72 + 8 * lg;
    f16x8 kh0 = *(const f16x8*)(KHA + ro);
    f16x8 kl0 = *(const f16x8*)(KLA + ro);
    f16x8 kh1 = *(const f16x8*)(KHA + ro + 32);
    f16x8 kl1 = *(const f16x8*)(KLA + ro + 32);
    sA[t] = __builtin_amdgcn_mfma_f32_16x16x32_f16(qah0, kh0, sA[t], 0, 0, 0);
    sA[t] = __builtin_amdgcn_mfma_f32_16x16x32_f16(qah0, kl0, sA[t], 0, 0, 0);
    sA[t] = __builtin_amdgcn_mfma_f32_16x16x32_f16(qal0, kh0, sA[t], 0, 0, 0);
    sA[t] = __builtin_amdgcn_mfma_f32_16x16x32_f16(qah1, kh1, sA[t], 0, 0, 0);
    sA[t] = __builtin_amdgcn_mfma_f32_16x16x32_f16(qah1, kl1, sA[t], 0, 0, 0);
    sA[t] = __builtin_amdgcn_mfma_f32_16x16x32_f16(qal1, kh1, sA[t], 0, 0, 0);
    f16x8 mh0 = *(const f16x8*)(KHB + ro);
    f16x8 ml0 = *(const f16x8*)(KLB + ro);
    f16x8 mh1 = *(const f16x8*)(KHB + ro + 32);
    f16x8 ml1 = *(const f16x8*)(KLB + ro + 32);
    sB[t] = __builtin_amdgcn_mfma_f32_16x16x32_f16(qbh0, mh0, sB[t], 0, 0, 0);
    sB[t] = __builtin_amdgcn_mfma_f32_16x16x32_f16(qbh0, ml0, sB[t], 0, 0, 0);
    sB[t] = __builtin_amdgcn_mfma_f32_16x16x32_f16(qbl0, mh0, sB[t], 0, 0, 0);
    sB[t] = __builtin_amdgcn_mfma_f32_16x16x32_f16(qbh1, mh1, sB[t], 0, 0, 0);
    sB[t] = __builtin_amdgcn_mfma_f32_16x16x32_f16(qbh1, ml1, sB[t], 0, 0, 0);
    sB[t] = __builtin_amdgcn_mfma_f32_16x16x32_f16(qbl1, mh1, sB[t], 0, 0, 0);
  }
  // ---- mean-fold correction + in-register softmax over k ----
  {
    float qra[4], qrb2[4];
#pragma unroll
    for (int reg = 0; reg < 4; ++reg) {
      qra[reg] = qsA[16 * w + 4 * lg + reg];
      qrb2[reg] = qsB[16 * w + 4 * lg + reg];
    }
#pragma unroll
    for (int t = 0; t < 4; ++t) {
      float mA_ = meanA[2 * t + (l15 >> 3)];
      float mB_ = meanB[2 * t + (l15 >> 3)];
#pragma unroll
      for (int reg = 0; reg < 4; ++reg) {
        sA[t][reg] -= qra[reg] * mA_;
        sB[t][reg] -= qrb2[reg] * mB_;
      }
    }
#pragma unroll
    for (int reg = 0; reg < 4; ++reg) {
      float ma = sA[0][reg], mb = sB[0][reg];
#pragma unroll
      for (int t = 1; t < 4; ++t) { ma = fmaxf(ma, sA[t][reg]); mb = fmaxf(mb, sB[t][reg]); }
#pragma unroll
      for (int m = 1; m <= 8; m <<= 1) {
        ma = fmaxf(ma, __shfl_xor(ma, m, 64));
        mb = fmaxf(mb, __shfl_xor(mb, m, 64));
      }
      float sa = 0.f, sb = 0.f;
#pragma unroll
      for (int t = 0; t < 4; ++t) {
        float ea = __expf(sA[t][reg] - ma), eb = __expf(sB[t][reg] - mb);
        sA[t][reg] = ea; sB[t][reg] = eb;
        sa += ea; sb += eb;
      }
#pragma unroll
      for (int m = 1; m <= 8; m <<= 1) {
        sa += __shfl_xor(sa, m, 64);
        sb += __shfl_xor(sb, m, 64);
      }
      float ra = 1.f / sa, rb = 1.f / sb;
#pragma unroll
      for (int t = 0; t < 4; ++t) { sA[t][reg] *= ra; sB[t][reg] *= rb; }
    }
  }
  __syncthreads();  // B2.5: all K reads done; overlay M32 onto K region

  // ---- write M fp32 (msw swizzle; serves both PV and m-map path) ----
#pragma unroll
  for (int t = 0; t < 4; ++t)
#pragma unroll
    for (int reg = 0; reg < 4; ++reg) {
      int jrow = 16 * w + 4 * lg + reg, kcol = 16 * t + l15;
      M32A[msw(jrow, kcol)] = sA[t][reg];
      M32B[msw(jrow, kcol)] = sB[t][reg];
    }
  __syncthreads();  // B3: M complete

  // ---- PV via MFMA (fp16 cvt from fp32 M): X^T[c][j] = sum_k V_sel[k][c] * M[j][k] ----
  f32x4 pL[4], pR[4];
#pragma unroll
  for (int t = 0; t < 4; ++t) { pL[t] = (f32x4){0.f, 0.f, 0.f, 0.f}; pR[t] = pL[t]; }
#pragma unroll
  for (int h = 0; h < 2; ++h) {
    f16x8 va = __builtin_bit_cast(f16x8, vAr[h]);
    f16x8 vb = __builtin_bit_cast(f16x8, vBr[h]);
#pragma unroll
    for (int jt = 0; jt < 4; ++jt) {
      const float* mra = M32A + msw(16 * jt + l15, 32 * h + 8 * lg);
      const float* mrb = M32B + msw(16 * jt + l15, 32 * h + 8 * lg);
      float fa[8], fb[8];
      *(float4*)&fa[0] = *(const float4*)mra;
      *(float4*)&fa[4] = *(const float4*)(mra + 4);
      *(float4*)&fb[0] = *(const float4*)mrb;
      *(float4*)&fb[4] = *(const float4*)(mrb + 4);
      f16x8 ma, mb;
#pragma unroll
      for (int e = 0; e < 8; ++e) { ma[e] = (_Float16)fa[e]; mb[e] = (_Float16)fb[e]; }
      pL[jt] = __builtin_amdgcn_mfma_f32_16x16x32_f16(va, ma, pL[jt], 0, 0, 0);
      pR[jt] = __builtin_amdgcn_mfma_f32_16x16x32_f16(vb, mb, pR[jt], 0, 0, 0);
    }
  }
  // ---- x blend prefetch (T14): issue loads before m_relax, use after B4 ----
  float xlv[4][4], xrv[4][4];
#pragma unroll
  for (int jt = 0; jt < 4; ++jt)
#pragma unroll
    for (int reg = 0; reg < 4; ++reg) {
      int c = 16 * w + 4 * lg + reg;
      int j = 16 * jt + l15;
      int hp2 = hb * 8 + (j >> 3), wp2 = wb * 8 + (j & 7);
      size_t off = ((size_t)(b * 64 + c)) * HW + hp2 * 512 + wp2;
      xlv[jt][reg] = xL[off];
      xrv[jt][reg] = xR[off];
    }
  // ---- m_relax band + einsum + tanh from fp32 M (128 threads) ----
  if (tid < 128) {
    int dir = tid >> 6, j = tid & 63;
    const float* Mrow = dir ? M32B : M32A;
    const float* Mcol = dir ? M32A : M32B;
    float acc = 0.f;
    for (int k = 0; k < 64; ++k) {
      float rx = 0.f;
#pragma unroll
      for (int i = -2; i <= 2; ++i) {
        int jj = j + i;
        if ((unsigned)jj < 64u) rx += Mrow[msw(jj, k)];
      }
      acc += rx * Mcol[msw(k, j)];
    }
    (dir ? mapR : mapL)[j] = tanhf(5.f * acc);
  }
  __syncthreads();  // B4: maps ready

  // ---- blend + store ----
#pragma unroll
  for (int jt = 0; jt < 4; ++jt) {
#pragma unroll
    for (int reg = 0; reg < 4; ++reg) {
      int c = 16 * w + 4 * lg + reg;
      int j = 16 * jt + l15;
      int hp2 = hb * 8 + (j >> 3), wp2 = wb * 8 + (j & 7);
      size_t off = ((size_t)(b * 64 + c)) * HW + hp2 * 512 + wp2;
      float ml = mapL[j], mr = mapR[j];
      outL[off] = xlv[jt][reg] * (1.f - ml) + pL[jt][reg] * ml;
      outR[off] = xrv[jt][reg] * (1.f - mr) + pR[jt][reg] * mr;
    }
  }
}

extern "C" void kernel_launch(void* const* d_in, const int* in_sizes, int n_in,
                              void* d_out, int out_size, void* d_ws, size_t ws_size,
                              hipStream_t stream) {
  const float* x_left = (const float*)d_in[0];
  const float* x_right = (const float*)d_in[1];
  const float* d_left = (const float*)d_in[2];
  const float* d_right = (const float*)d_in[3];
  const float* bn_gamma = (const float*)d_in[4];
  const float* bn_beta = (const float*)d_in[5];
  const float* rb_w1 = (const float*)d_in[6];
  const float* rb_b1 = (const float*)d_in[7];
  const float* rb_w2 = (const float*)d_in[8];
  const float* rb_b2 = (const float*)d_in[9];
  const float* qkv_w = (const float*)d_in[10];
  const float* qkv_b = (const float*)d_in[11];

  float* ws = (float*)d_ws;
  const size_t S = S_ELEMS;
  unsigned short* tL = (unsigned short*)ws;              // S ushorts (conv1 out fp16)
  unsigned short* tR = tL + S;                           // S ushorts (ends at ws+S floats)
  float* knL = ws + 2 * S;           // S floats NHWC [b*HW+p][64]
  float* knR = ws + 3 * S;           // S floats
  unsigned short* vnL = (unsigned short*)(ws + 4 * S);   // S ushorts NHWC
  unsigned short* vnR = vnL + S;                         // S ushorts
  float* qnL = ws + 5 * S;           // S floats NHWC
  float* qnR = ws + 6 * S;           // S floats

  // partial/stats at head of d_out: written by bn kernels, read by conv kernels,
  // overwritten by attn's blend at the end (stream order guarantees safety).
  float* out_left = (float*)d_out;
  float* out_right = out_left + S;
  float2* partial = (float2*)d_out;              // 2048 float2
  float* stats = (float*)d_out + 4096;           // 256 floats

  bn_part_k<<<2048, 256, 0, stream>>>(x_left, x_right, partial);
  bn_fin_k<<<1, 128, 0, stream>>>(partial, bn_gamma, bn_beta, stats);

  conv1_k<<<8192, 256, 0, stream>>>(x_left, x_right, rb_w1, rb_b1, stats, tL, tR);
  conv2_qkv_k<<<8192, 256, 0, stream>>>(tL, tR, x_left, x_right, rb_w2, rb_b2,
                                        qkv_w, qkv_b, stats,
                                        qnL, qnR, knL, knR, vnL, vnR);
  attn_k<<<4096, 256, 0, stream>>>(qnL, qnR, knL, knR, vnL, vnR,
                                   d_left, d_right, x_left, x_right,
                                   out_left, out_right);
}

// Round 20
// 608.065 us; speedup vs baseline: 1.9875x; 1.1581x over previous
//
#include <hip/hip_runtime.h>
#include <cstdint>

#define HW 131072        // H*W
#define S_ELEMS 16777216 // B*C*H*W

typedef __attribute__((ext_vector_type(8))) _Float16 f16x8;
typedef __attribute__((ext_vector_type(4))) _Float16 f16x4;
typedef __attribute__((ext_vector_type(4))) float f32x4;

__device__ __forceinline__ float h2f(unsigned short u) {
  return (float)__builtin_bit_cast(_Float16, u);
}
__device__ __forceinline__ unsigned short f2h(float f) {
  return __builtin_bit_cast(unsigned short, (_Float16)f);
}
// M32 bank swizzle: XOR col 8-blocks by row-class; kills j/j+8/j+16/j+24 bank aliasing
// while keeping 8-float blocks contiguous (float4-aligned reads still valid).
__device__ __forceinline__ int msw(int r, int c) {
  return r * 68 + (c ^ (((r >> 3) & 3) << 3));
}

// ---------------- BN stats stage 1: partial sums (2 sides x 64 c x 16 slabs) ----------------
__global__ __launch_bounds__(256) void bn_part_k(const float* __restrict__ xL,
                                                 const float* __restrict__ xR,
                                                 float2* __restrict__ partial) {
  int bid = blockIdx.x;
  int side = bid >> 10, rest = bid & 1023;
  int c = rest >> 4, sl = rest & 15;
  const float* x = side ? xR : xL;
  const float4* p = (const float4*)(x + ((size_t)((sl >> 3) * 64 + c)) * HW + (size_t)(sl & 7) * 16384);
  float s1 = 0.f, s2 = 0.f;
  for (int i = threadIdx.x; i < 4096; i += 256) {
    float4 v = p[i];
    s1 += v.x + v.y + v.z + v.w;
    s2 += v.x * v.x + v.y * v.y + v.z * v.z + v.w * v.w;
  }
  for (int m = 32; m; m >>= 1) {
    s1 += __shfl_xor(s1, m, 64);
    s2 += __shfl_xor(s2, m, 64);
  }
  __shared__ float r1[4], r2[4];
  int wv = threadIdx.x >> 6;
  if ((threadIdx.x & 63) == 0) { r1[wv] = s1; r2[wv] = s2; }
  __syncthreads();
  if (threadIdx.x == 0) {
    partial[bid] = make_float2(r1[0] + r1[1] + r1[2] + r1[3], r2[0] + r2[1] + r2[2] + r2[3]);
  }
}

// ---------------- BN stats stage 2: finalize scale/shift ----------------
__global__ __launch_bounds__(128) void bn_fin_k(const float2* __restrict__ partial,
                                                const float* __restrict__ gamma,
                                                const float* __restrict__ beta,
                                                float* __restrict__ stats) {
  int tid = threadIdx.x;  // 0..127: side*64 + c
  int side = tid >> 6, c = tid & 63;
  float s1 = 0.f, s2 = 0.f;
  const float2* p = partial + (side * 1024 + c * 16);
  for (int s = 0; s < 16; ++s) { float2 v = p[s]; s1 += v.x; s2 += v.y; }
  float mu = s1 / 262144.f;
  float var = s2 / 262144.f - mu * mu;
  float rs = rsqrtf(var + 1e-5f);
  float sc = rs * gamma[c];
  stats[side * 128 + c] = sc;
  stats[side * 128 + 64 + c] = beta[c] - mu * sc;
}

// ---------------- conv1 via MFMA implicit GEMM: bn(x) fp16 -> 9-tap MFMA -> leaky -> t fp16 --
// Same fragment mapping as conv2_qkv (proven round 19). Input fp16-exact, only W split hi/lo.
__global__ __launch_bounds__(256) void conv1_k(const float* __restrict__ xL,
                                               const float* __restrict__ xR,
                                               const float* __restrict__ wgt,
                                               const float* __restrict__ bias,
                                               const float* __restrict__ stats,
                                               unsigned short* __restrict__ tL,
                                               unsigned short* __restrict__ tR) {
  // ci-stride 372 ushorts -> fragment reads bank-spread (same as conv2)
  __shared__ __align__(16) unsigned short sInH[16 * 372];
  __shared__ __align__(16) float sW1r[2304];  // raw w1 [o][ci][9]
  __shared__ float sB1[16], sSc[16], sSh[16];
  int bid = blockIdx.x;
  int side = bid >> 12, rest = bid & 4095;
  int tw = rest & 15, th = (rest >> 4) & 31, g = (rest >> 9) & 3, b = rest >> 11;
  const float* in = side ? xR : xL;
  unsigned short* out = side ? tR : tL;
  const float* ss = stats + side * 128;
  int tid = threadIdx.x;
  const int lane = tid & 63, wv = tid >> 6;
  const int l15 = lane & 15, lg = lane >> 4;

  for (int e = tid; e < 2304; e += 256) sW1r[e] = wgt[g * 2304 + e];
  if (tid < 16) {
    sB1[tid] = bias[g * 16 + tid];
    sSc[tid] = ss[g * 16 + tid];
    sSh[tid] = ss[64 + g * 16 + tid];
  }
  __syncthreads();  // RACE FIX: sSc/sSh visible before staging reads them
  int h0 = th * 8 - 1, w0 = tw * 32 - 1;
  const float* inb = in + ((size_t)(b * 64 + g * 16)) * HW;
  for (int e = tid; e < 5440; e += 256) {
    int ci = e / 340, rem = e - ci * 340, r = rem / 34, c = rem - r * 34;
    int h = h0 + r, w = w0 + c;
    unsigned short v = 0;
    if ((unsigned)h < 256u && (unsigned)w < 512u) {
      v = f2h(inb[(size_t)ci * HW + h * 512 + w] * sSc[ci] + sSh[ci]);
    }
    sInH[ci * 372 + r * 36 + c] = v;
  }
  __syncthreads();

  // hoist W1 tap fragments (hi/lo): A-frag lane holds W[oc=l15][ci=4lg+i]
  f16x4 W1H[9], W1L[9];
#pragma unroll
  for (int tap = 0; tap < 9; ++tap) {
#pragma unroll
    for (int i = 0; i < 4; ++i) {
      float f = sW1r[l15 * 144 + (4 * lg + i) * 9 + tap];
      _Float16 h = (_Float16)f;
      W1H[tap][i] = h;
      W1L[tap][i] = (_Float16)(f - (float)h);
    }
  }
  float b14[4];
#pragma unroll
  for (int r = 0; r < 4; ++r) b14[r] = sB1[4 * lg + r];

  // per 16-px column block: 9-tap MFMA -> leaky -> f2h -> planar store
#pragma unroll
  for (int j = 0; j < 4; ++j) {
    int ct = 4 * wv + j;
    int px = ct * 16 + l15;
    int prow = px >> 5, pcol = px & 31;
    const unsigned short* p0 = sInH + (4 * lg) * 372 + prow * 36 + pcol;
    f32x4 acc;
#pragma unroll
    for (int r = 0; r < 4; ++r) acc[r] = b14[r];
#pragma unroll
    for (int kh = 0; kh < 3; ++kh) {
#pragma unroll
      for (int kw = 0; kw < 3; ++kw) {
        int toff = kh * 36 + kw;
        f16x4 it;
#pragma unroll
        for (int i = 0; i < 4; ++i)
          it[i] = __builtin_bit_cast(_Float16, p0[i * 372 + toff]);
        acc = __builtin_amdgcn_mfma_f32_16x16x16f16(W1H[kh * 3 + kw], it, acc, 0, 0, 0);
        acc = __builtin_amdgcn_mfma_f32_16x16x16f16(W1L[kh * 3 + kw], it, acc, 0, 0, 0);
      }
    }
    int hpix = th * 8 + prow, wpix = tw * 32 + pcol;
    size_t rowoff = (size_t)hpix * 512 + wpix;
#pragma unroll
    for (int r = 0; r < 4; ++r) {
      float a = acc[r];
      a = a > 0.f ? a : 0.1f * a;
      out[((size_t)(b * 64 + g * 16 + 4 * lg + r)) * HW + rowoff] = f2h(a);
    }
  }
}

// ---------------- fused conv2(MFMA implicit GEMM) + residual + qkv(MFMA); both sides --------
// conv2 = 9 taps of W_tap[16][16] . I_shift[16][256] via 16x16x16 MFMA.
// Chaining identity: conv2 D-frag (lane: oc=4lg+reg @ px=ct*16+l15) == qkv B-frag
// (lane: ci=4lg+i @ same px) -> accumulator feeds qkv directly, no LDS round trip.
__global__ __launch_bounds__(256) void conv2_qkv_k(
    const unsigned short* __restrict__ tL, const unsigned short* __restrict__ tR,
    const float* __restrict__ xL, const float* __restrict__ xR,
    const float* __restrict__ w2g, const float* __restrict__ b2g,
    const float* __restrict__ wq, const float* __restrict__ bq,
    const float* __restrict__ stats,
    float* __restrict__ qnL, float* __restrict__ qnR,
    float* __restrict__ knL, float* __restrict__ knR,
    unsigned short* __restrict__ vnL, unsigned short* __restrict__ vnR) {
  // ci-stride 372 ushorts: lg stride = 4*372/2 words = 744 % 32 = 8 -> full bank spread
  __shared__ __align__(16) unsigned short sInH[16 * 372];  // conv1-out fp16 tile +1 halo
  __shared__ __align__(16) float sW2r[2304];               // raw w2 [o][ci][9]
  __shared__ __align__(16) float sWq[768];
  __shared__ float sB2[16], sBq[48], sSc[16], sSh[16];

  int bid = blockIdx.x;
  int side = bid >> 12, rest = bid & 4095;
  int tw = rest & 15, th = (rest >> 4) & 31, g = (rest >> 9) & 3, b = rest >> 11;
  const unsigned short* t = side ? tR : tL;
  const float* x = side ? xR : xL;
  float* qn = side ? qnR : qnL;
  float* kn = side ? knR : knL;
  unsigned short* vn = side ? vnR : vnL;
  const float* ss = stats + side * 128;
  int tid = threadIdx.x;
  const int lane = tid & 63, wv = tid >> 6;
  const int l15 = lane & 15, lg = lane >> 4;

  // early residual prefetch (T14), in D layout: oc=4lg+r, px=ct*16+l15
  float resx[4][4];
#pragma unroll
  for (int j = 0; j < 4; ++j) {
    int px = (4 * wv + j) * 16 + l15;
    int hpix = th * 8 + (px >> 5), wpix = tw * 32 + (px & 31);
    size_t rowoff = (size_t)hpix * 512 + wpix;
#pragma unroll
    for (int r = 0; r < 4; ++r)
      resx[j][r] = x[((size_t)(b * 64 + g * 16 + 4 * lg + r)) * HW + rowoff];
  }

  // stage weights / biases / bn scale-shift
  for (int e = tid; e < 2304; e += 256) sW2r[e] = w2g[g * 2304 + e];
  for (int e = tid; e < 768; e += 256) {
    int oo = e >> 4, ci = e & 15;
    sWq[e] = wq[(g * 48 + oo) * 16 + ci];
  }
  if (tid < 48) sBq[tid] = bq[g * 48 + tid];
  if (tid < 16) {
    sB2[tid] = b2g[g * 16 + tid];
    sSc[tid] = ss[g * 16 + tid];
    sSh[tid] = ss[64 + g * 16 + tid];
  }

  // stage conv1-out tile (1-halo) from global fp16 -> LDS fp16 (padded stride)
  int h0 = th * 8 - 1, w0 = tw * 32 - 1;
  const unsigned short* inb = t + ((size_t)(b * 64 + g * 16)) * HW;
  for (int e = tid; e < 5440; e += 256) {
    int ci = e / 340, rem = e - ci * 340, r = rem / 34, c = rem - r * 34;
    int h = h0 + r, w = w0 + c;
    unsigned short v = 0;
    if ((unsigned)h < 256u && (unsigned)w < 512u) {
      v = inb[(size_t)ci * HW + h * 512 + w];
    }
    sInH[ci * 372 + r * 36 + c] = v;
  }
  __syncthreads();  // weights + tile staged (single barrier; nothing else writes LDS)

  // hoist A fragments: W2 taps (hi/lo split) + Wq (hi/lo)
  f16x4 W2H[9], W2L[9];
#pragma unroll
  for (int tap = 0; tap < 9; ++tap) {
#pragma unroll
    for (int i = 0; i < 4; ++i) {
      float f = sW2r[l15 * 144 + (4 * lg + i) * 9 + tap];
      _Float16 h = (_Float16)f;
      W2H[tap][i] = h;
      W2L[tap][i] = (_Float16)(f - (float)h);
    }
  }
  f16x4 WqH[3], WqL[3];
#pragma unroll
  for (int rt = 0; rt < 3; ++rt) {
    float4 wvv = *(const float4*)(sWq + (rt * 16 + l15) * 16 + 4 * lg);
#pragma unroll
    for (int i = 0; i < 4; ++i) {
      float f = ((float*)&wvv)[i];
      _Float16 h = (_Float16)f;
      WqH[rt][i] = h;
      WqL[rt][i] = (_Float16)(f - (float)h);
    }
  }
  float sc4[4], sh4[4], b24[4];
#pragma unroll
  for (int r = 0; r < 4; ++r) {
    sc4[r] = sSc[4 * lg + r];
    sh4[r] = sSh[4 * lg + r];
    b24[r] = sB2[4 * lg + r];
  }

  // per 16-px column block: conv2 MFMA -> residual -> split -> qkv MFMA -> store
#pragma unroll
  for (int j = 0; j < 4; ++j) {
    int ct = 4 * wv + j;
    int px = ct * 16 + l15;
    int prow = px >> 5, pcol = px & 31;
    const unsigned short* p0 = sInH + 0 * 372 + (4 * lg) * 372 + prow * 36 + pcol;
    f32x4 acc;
#pragma unroll
    for (int r = 0; r < 4; ++r) acc[r] = b24[r];
#pragma unroll
    for (int kh = 0; kh < 3; ++kh) {
#pragma unroll
      for (int kw = 0; kw < 3; ++kw) {
        int toff = kh * 36 + kw;
        f16x4 it;
#pragma unroll
        for (int i = 0; i < 4; ++i)
          it[i] = __builtin_bit_cast(_Float16, p0[i * 372 + toff]);
        acc = __builtin_amdgcn_mfma_f32_16x16x16f16(W2H[kh * 3 + kw], it, acc, 0, 0, 0);
        acc = __builtin_amdgcn_mfma_f32_16x16x16f16(W2L[kh * 3 + kw], it, acc, 0, 0, 0);
      }
    }
#pragma unroll
    for (int r = 0; r < 4; ++r) acc[r] += resx[j][r] * sc4[r] + sh4[r];
    // split r fragment (conv2 D == qkv B mapping: lane holds ci=4lg+i at px)
    f16x4 rh, rl;
#pragma unroll
    for (int i = 0; i < 4; ++i) {
      _Float16 h = (_Float16)acc[i];
      rh[i] = h;
      rl[i] = (_Float16)(acc[i] - (float)h);
    }
    int hpix = th * 8 + prow, wpix = tw * 32 + pcol;
    size_t pxbase = ((size_t)b * HW + hpix * 512 + wpix) * 64;
#pragma unroll
    for (int rt = 0; rt < 3; ++rt) {
      f32x4 a;
#pragma unroll
      for (int r = 0; r < 4; ++r) a[r] = sBq[rt * 16 + 4 * lg + r];
      a = __builtin_amdgcn_mfma_f32_16x16x16f16(WqH[rt], rh, a, 0, 0, 0);
      a = __builtin_amdgcn_mfma_f32_16x16x16f16(WqH[rt], rl, a, 0, 0, 0);
      a = __builtin_amdgcn_mfma_f32_16x16x16f16(WqL[rt], rh, a, 0, 0, 0);
      int ob = g * 48 + rt * 16 + 4 * lg;
      if (ob < 64) {
        *(float4*)(qn + pxbase + ob) = *(float4*)&a;
      } else if (ob < 128) {
        *(float4*)(kn + pxbase + (ob - 64)) = *(float4*)&a;
      } else {
        uint2 pk;
        pk.x = (uint32_t)f2h(a[0]) | ((uint32_t)f2h(a[1]) << 16);
        pk.y = (uint32_t)f2h(a[2]) | ((uint32_t)f2h(a[3]) << 16);
        *(uint2*)(vn + pxbase + (ob - 128)) = pk;
      }
    }
  }
}

// ---------------- fused per-window attention: split-fp16 MFMA, all-NHWC, XCD swizzle ----
__global__ __launch_bounds__(256, 4) void attn_k(
    const float* __restrict__ qLn, const float* __restrict__ qRn,  // NHWC fp32
    const float* __restrict__ kLn, const float* __restrict__ kRn,  // NHWC fp32
    const unsigned short* __restrict__ vLn, const unsigned short* __restrict__ vRn, // NHWC fp16
    const float* __restrict__ dL, const float* __restrict__ dR,
    const float* __restrict__ xL, const float* __restrict__ xR,
    float* outL, float* outR) {
  // XCD-aware swizzle: consecutive windows -> same XCD L2 (4096 % 8 == 0, bijective)
  const int orig = blockIdx.x;
  const int n = (orig & 7) * 512 + (orig >> 3);
  const int b = n >> 11, hb = (n >> 6) & 31, wb = n & 63;
  const int tid = threadIdx.x;
  const int lane = tid & 63, w = tid >> 6;
  const int l15 = lane & 15, lg = lane >> 4;

  // K hi/lo (stride 72, fp16) — region reused after QK^T as fp32 M (stride 68, msw-swizzled)
  __shared__ __align__(16) unsigned short sK[4 * 64 * 72];   // 36864 B
  __shared__ float meanA[8], meanB[8], qsA[64], qsB[64], mapL[64], mapR[64];
  unsigned short* KHA = sK;
  unsigned short* KLA = sK + 64 * 72;
  unsigned short* KHB = sK + 2 * 64 * 72;
  unsigned short* KLB = sK + 3 * 64 * 72;
  float* M32A = (float*)sK;           // [64][68] msw layout
  float* M32B = (float*)sK + 64 * 68; // [64][68]

  const float* dLb = dL + (size_t)b * HW;
  const float* dRb = dR + (size_t)b * HW;
  const size_t nb = (size_t)b * HW;

  // ---- K gather (NHWC): 2 iters, 8 channels per thread per dir ----
  const int cc0 = (wb & 7) * 8;
#pragma unroll
  for (int it = 0; it < 2; ++it) {
    int slot = tid + 256 * it;           // 0..511
    int c2 = slot & 63, k8 = slot >> 6;  // k8 0..7
    int hh = 4 * c2 + (hb >> 3);
    int ww = (hb & 7) * 64 + k8 * 8 + (wb >> 3);
    int dpos = hh * 512 + ww;
    int iwr = ww - (int)dLb[dpos]; iwr = min(max(iwr, 0), 511);
    int iwl = ww + (int)dRb[dpos]; iwl = min(max(iwl, 0), 511);
    const float* pr = kRn + (nb + hh * 512 + iwr) * 64 + cc0;
    const float* pl = kLn + (nb + hh * 512 + iwl) * 64 + cc0;
    float fr[8], fl[8];
    *(float4*)&fr[0] = *(const float4*)pr;
    *(float4*)&fr[4] = *(const float4*)(pr + 4);
    *(float4*)&fl[0] = *(const float4*)pl;
    *(float4*)&fl[4] = *(const float4*)(pl + 4);
#pragma unroll
    for (int kl = 0; kl < 8; ++kl) {
      int k = 8 * k8 + kl;
      unsigned short hr = f2h(fr[kl]), hl = f2h(fl[kl]);
      KHA[k * 72 + c2] = hr; KLA[k * 72 + c2] = f2h(fr[kl] - h2f(hr));
      KHB[k * 72 + c2] = hl; KLB[k * 72 + c2] = f2h(fl[kl] - h2f(hl));
    }
  }

  // ---- Q load (NHWC fp32) + hi/lo split ----
  const int jr = 16 * w + l15;
  const int hp = hb * 8 + (jr >> 3), wp = wb * 8 + (jr & 7);
  const int gpix = hp * 512 + wp;
  const float* qlp = qLn + (nb + gpix) * 64;
  const float* qrp = qRn + (nb + gpix) * 64;
  float qv0[8], qv1[8], qw0[8], qw1[8];
  *(float4*)&qv0[0] = *(const float4*)(qlp + 8 * lg);
  *(float4*)&qv0[4] = *(const float4*)(qlp + 8 * lg + 4);
  *(float4*)&qv1[0] = *(const float4*)(qlp + 32 + 8 * lg);
  *(float4*)&qv1[4] = *(const float4*)(qlp + 32 + 8 * lg + 4);
  *(float4*)&qw0[0] = *(const float4*)(qrp + 8 * lg);
  *(float4*)&qw0[4] = *(const float4*)(qrp + 8 * lg + 4);
  *(float4*)&qw1[0] = *(const float4*)(qrp + 32 + 8 * lg);
  *(float4*)&qw1[4] = *(const float4*)(qrp + 32 + 8 * lg + 4);
  f16x8 qah0, qal0, qah1, qal1, qbh0, qbl0, qbh1, qbl1;
#pragma unroll
  for (int e = 0; e < 8; ++e) {
    _Float16 h;
    h = (_Float16)qv0[e]; qah0[e] = h; qal0[e] = (_Float16)(qv0[e] - (float)h);
    h = (_Float16)qv1[e]; qah1[e] = h; qal1[e] = (_Float16)(qv1[e] - (float)h);
    h = (_Float16)qw0[e]; qbh0[e] = h; qbl0[e] = (_Float16)(qw0[e] - (float)h);
    h = (_Float16)qw1[e]; qbh1[e] = h; qbl1[e] = (_Float16)(qw1[e] - (float)h);
  }

  // ---- V fragments (NHWC fp16: one b128 per (h,dir)) ----
  int4 vAr[2], vBr[2];
  {
    const int cv = 16 * w + l15;
#pragma unroll
    for (int h = 0; h < 2; ++h) {
      int hi = 4 * h + lg;
      int hh = 4 * cv + (hb >> 3);
      int ww = (hb & 7) * 64 + hi * 8 + (wb >> 3);
      int dpos = hh * 512 + ww;
      int iwr = ww - (int)dLb[dpos]; iwr = min(max(iwr, 0), 511);
      int iwl = ww + (int)dRb[dpos]; iwl = min(max(iwl, 0), 511);
      vAr[h] = *(const int4*)(vRn + (nb + hh * 512 + iwr) * 64 + cc0);
      vBr[h] = *(const int4*)(vLn + (nb + hh * 512 + iwl) * 64 + cc0);
    }
  }
  __syncthreads();  // B1: K staged

  // ---- K means per (dir,hi) over (wi,c): exact = hi+lo ----
  {
    int grp = tid >> 4, i = tid & 15;
    int dir = grp >> 3, hi = grp & 7;
    int off0 = (8 * hi + (i >> 1)) * 72 + (i & 1) * 32;
    const unsigned short* srcH = (dir ? KHB : KHA) + off0;
    const unsigned short* srcL = (dir ? KLB : KLA) + off0;
    float s = 0.f;
#pragma unroll
    for (int q = 0; q < 32; ++q) s += h2f(srcH[q]) + h2f(srcL[q]);
    for (int m = 8; m; m >>= 1) s += __shfl_xor(s, m, 64);
    if (i == 0) (dir ? meanB : meanA)[hi] = s * (1.f / 512.f);
  }
  // ---- qsum[j] (fp32 exact) ----
  {
    float sa = 0.f, sb = 0.f;
#pragma unroll
    for (int e = 0; e < 8; ++e) {
      sa += qv0[e] + qv1[e];
      sb += qw0[e] + qw1[e];
    }
    sa += __shfl_xor(sa, 16, 64); sa += __shfl_xor(sa, 32, 64);
    sb += __shfl_xor(sb, 16, 64); sb += __shfl_xor(sb, 32, 64);
    if (lane < 16) { qsA[jr] = sa; qsB[jr] = sb; }
  }
  __syncthreads();  // B2: means + qsums ready

  // ---- QK^T via split-fp16 MFMA: q.k ~= qh.kh + qh.kl + ql.kh ----
  f32x4 sA[4], sB[4];
#pragma unroll
  for (int t = 0; t < 4; ++t) { sA[t] = (f32x4){0.f, 0.f, 0.f, 0.f}; sB[t] = sA[t]; }
#pragma unroll
  for (int t = 0; t < 4; ++t) {
    int ro = (16 * t + l15) * 72 + 8 * lg;
    f16x8 kh0 = *(const f16x8*)(KHA + ro);
    f16x8 kl0 = *(const f16x8*)(KLA + ro);
    f16x8 kh1 = *(const f16x8*)(KHA + ro + 32);
    f16x8 kl1 = *(const f16x8*)(KLA + ro + 32);
    sA[t] = __builtin_amdgcn_mfma_f32_16x16x32_f16(qah0, kh0, sA[t], 0, 0, 0);
    sA[t] = __builtin_amdgcn_mfma_f32_16x16x32_f16(qah0, kl0, sA[t], 0, 0, 0);
    sA[t] = __builtin_amdgcn_mfma_f32_16x16x32_f16(qal0, kh0, sA[t], 0, 0, 0);
    sA[t] = __builtin_amdgcn_mfma_f32_16x16x32_f16(qah1, kh1, sA[t], 0, 0, 0);
    sA[t] = __builtin_amdgcn_mfma_f32_16x16x32_f16(qah1, kl1, sA[t], 0, 0, 0);
    sA[t] = __builtin_amdgcn_mfma_f32_16x16x32_f16(qal1, kh1, sA[t], 0, 0, 0);
    f16x8 mh0 = *(const f16x8*)(KHB + ro);
    f16x8 ml0 = *(const f16x8*)(KLB + ro);
    f16x8 mh1 = *(const f16x8*)(KHB + ro + 32);
    f16x8 ml1 = *(const f16x8*)(KLB + ro + 32);
    sB[t] = __builtin_amdgcn_mfma_f32_16x16x32_f16(qbh0, mh0, sB[t], 0, 0, 0);
    sB[t] = __builtin_amdgcn_mfma_f32_16x16x32_f16(qbh0, ml0, sB[t], 0, 0, 0);
    sB[t] = __builtin_amdgcn_mfma_f32_16x16x32_f16(qbl0, mh0, sB[t], 0, 0, 0);
    sB[t] = __builtin_amdgcn_mfma_f32_16x16x32_f16(qbh1, mh1, sB[t], 0, 0, 0);
    sB[t] = __builtin_amdgcn_mfma_f32_16x16x32_f16(qbh1, ml1, sB[t], 0, 0, 0);
    sB[t] = __builtin_amdgcn_mfma_f32_16x16x32_f16(qbl1, mh1, sB[t], 0, 0, 0);
  }
  // ---- mean-fold correction + in-register softmax over k ----
  {
    float qra[4], qrb2[4];
#pragma unroll
    for (int reg = 0; reg < 4; ++reg) {
      qra[reg] = qsA[16 * w + 4 * lg + reg];
      qrb2[reg] = qsB[16 * w + 4 * lg + reg];
    }
#pragma unroll
    for (int t = 0; t < 4; ++t) {
      float mA_ = meanA[2 * t + (l15 >> 3)];
      float mB_ = meanB[2 * t + (l15 >> 3)];
#pragma unroll
      for (int reg = 0; reg < 4; ++reg) {
        sA[t][reg] -= qra[reg] * mA_;
        sB[t][reg] -= qrb2[reg] * mB_;
      }
    }
#pragma unroll
    for (int reg = 0; reg < 4; ++reg) {
      float ma = sA[0][reg], mb = sB[0][reg];
#pragma unroll
      for (int t = 1; t < 4; ++t) { ma = fmaxf(ma, sA[t][reg]); mb = fmaxf(mb, sB[t][reg]); }
#pragma unroll
      for (int m = 1; m <= 8; m <<= 1) {
        ma = fmaxf(ma, __shfl_xor(ma, m, 64));
        mb = fmaxf(mb, __shfl_xor(mb, m, 64));
      }
      float sa = 0.f, sb = 0.f;
#pragma unroll
      for (int t = 0; t < 4; ++t) {
        float ea = __expf(sA[t][reg] - ma), eb = __expf(sB[t][reg] - mb);
        sA[t][reg] = ea; sB[t][reg] = eb;
        sa += ea; sb += eb;
      }
#pragma unroll
      for (int m = 1; m <= 8; m <<= 1) {
        sa += __shfl_xor(sa, m, 64);
        sb += __shfl_xor(sb, m, 64);
      }
      float ra = 1.f / sa, rb = 1.f / sb;
#pragma unroll
      for (int t = 0; t < 4; ++t) { sA[t][reg] *= ra; sB[t][reg] *= rb; }
    }
  }
  __syncthreads();  // B2.5: all K reads done; overlay M32 onto K region

  // ---- write M fp32 (msw swizzle; serves both PV and m-map path) ----
#pragma unroll
  for (int t = 0; t < 4; ++t)
#pragma unroll
    for (int reg = 0; reg < 4; ++reg) {
      int jrow = 16 * w + 4 * lg + reg, kcol = 16 * t + l15;
      M32A[msw(jrow, kcol)] = sA[t][reg];
      M32B[msw(jrow, kcol)] = sB[t][reg];
    }
  __syncthreads();  // B3: M complete

  // ---- PV via MFMA (fp16 cvt from fp32 M): X^T[c][j] = sum_k V_sel[k][c] * M[j][k] ----
  f32x4 pL[4], pR[4];
#pragma unroll
  for (int t = 0; t < 4; ++t) { pL[t] = (f32x4){0.f, 0.f, 0.f, 0.f}; pR[t] = pL[t]; }
#pragma unroll
  for (int h = 0; h < 2; ++h) {
    f16x8 va = __builtin_bit_cast(f16x8, vAr[h]);
    f16x8 vb = __builtin_bit_cast(f16x8, vBr[h]);
#pragma unroll
    for (int jt = 0; jt < 4; ++jt) {
      const float* mra = M32A + msw(16 * jt + l15, 32 * h + 8 * lg);
      const float* mrb = M32B + msw(16 * jt + l15, 32 * h + 8 * lg);
      float fa[8], fb[8];
      *(float4*)&fa[0] = *(const float4*)mra;
      *(float4*)&fa[4] = *(const float4*)(mra + 4);
      *(float4*)&fb[0] = *(const float4*)mrb;
      *(float4*)&fb[4] = *(const float4*)(mrb + 4);
      f16x8 ma, mb;
#pragma unroll
      for (int e = 0; e < 8; ++e) { ma[e] = (_Float16)fa[e]; mb[e] = (_Float16)fb[e]; }
      pL[jt] = __builtin_amdgcn_mfma_f32_16x16x32_f16(va, ma, pL[jt], 0, 0, 0);
      pR[jt] = __builtin_amdgcn_mfma_f32_16x16x32_f16(vb, mb, pR[jt], 0, 0, 0);
    }
  }
  // ---- x blend prefetch (T14): issue loads before m_relax, use after B4 ----
  float xlv[4][4], xrv[4][4];
#pragma unroll
  for (int jt = 0; jt < 4; ++jt)
#pragma unroll
    for (int reg = 0; reg < 4; ++reg) {
      int c = 16 * w + 4 * lg + reg;
      int j = 16 * jt + l15;
      int hp2 = hb * 8 + (j >> 3), wp2 = wb * 8 + (j & 7);
      size_t off = ((size_t)(b * 64 + c)) * HW + hp2 * 512 + wp2;
      xlv[jt][reg] = xL[off];
      xrv[jt][reg] = xR[off];
    }
  // ---- m_relax band + einsum + tanh from fp32 M (128 threads) ----
  if (tid < 128) {
    int dir = tid >> 6, j = tid & 63;
    const float* Mrow = dir ? M32B : M32A;
    const float* Mcol = dir ? M32A : M32B;
    float acc = 0.f;
    for (int k = 0; k < 64; ++k) {
      float rx = 0.f;
#pragma unroll
      for (int i = -2; i <= 2; ++i) {
        int jj = j + i;
        if ((unsigned)jj < 64u) rx += Mrow[msw(jj, k)];
      }
      acc += rx * Mcol[msw(k, j)];
    }
    (dir ? mapR : mapL)[j] = tanhf(5.f * acc);
  }
  __syncthreads();  // B4: maps ready

  // ---- blend + store ----
#pragma unroll
  for (int jt = 0; jt < 4; ++jt) {
#pragma unroll
    for (int reg = 0; reg < 4; ++reg) {
      int c = 16 * w + 4 * lg + reg;
      int j = 16 * jt + l15;
      int hp2 = hb * 8 + (j >> 3), wp2 = wb * 8 + (j & 7);
      size_t off = ((size_t)(b * 64 + c)) * HW + hp2 * 512 + wp2;
      float ml = mapL[j], mr = mapR[j];
      outL[off] = xlv[jt][reg] * (1.f - ml) + pL[jt][reg] * ml;
      outR[off] = xrv[jt][reg] * (1.f - mr) + pR[jt][reg] * mr;
    }
  }
}

extern "C" void kernel_launch(void* const* d_in, const int* in_sizes, int n_in,
                              void* d_out, int out_size, void* d_ws, size_t ws_size,
                              hipStream_t stream) {
  const float* x_left = (const float*)d_in[0];
  const float* x_right = (const float*)d_in[1];
  const float* d_left = (const float*)d_in[2];
  const float* d_right = (const float*)d_in[3];
  const float* bn_gamma = (const float*)d_in[4];
  const float* bn_beta = (const float*)d_in[5];
  const float* rb_w1 = (const float*)d_in[6];
  const float* rb_b1 = (const float*)d_in[7];
  const float* rb_w2 = (const float*)d_in[8];
  const float* rb_b2 = (const float*)d_in[9];
  const float* qkv_w = (const float*)d_in[10];
  const float* qkv_b = (const float*)d_in[11];

  float* ws = (float*)d_ws;
  const size_t S = S_ELEMS;
  unsigned short* tL = (unsigned short*)ws;              // S ushorts (conv1 out fp16)
  unsigned short* tR = tL + S;                           // S ushorts (ends at ws+S floats)
  float* knL = ws + 2 * S;           // S floats NHWC [b*HW+p][64]
  float* knR = ws + 3 * S;           // S floats
  unsigned short* vnL = (unsigned short*)(ws + 4 * S);   // S ushorts NHWC
  unsigned short* vnR = vnL + S;                         // S ushorts
  float* qnL = ws + 5 * S;           // S floats NHWC
  float* qnR = ws + 6 * S;           // S floats

  // partial/stats at head of d_out: written by bn kernels, read by conv kernels,
  // overwritten by attn's blend at the end (stream order guarantees safety).
  float* out_left = (float*)d_out;
  float* out_right = out_left + S;
  float2* partial = (float2*)d_out;              // 2048 float2
  float* stats = (float*)d_out + 4096;           // 256 floats

  bn_part_k<<<2048, 256, 0, stream>>>(x_left, x_right, partial);
  bn_fin_k<<<1, 128, 0, stream>>>(partial, bn_gamma, bn_beta, stats);

  conv1_k<<<8192, 256, 0, stream>>>(x_left, x_right, rb_w1, rb_b1, stats, tL, tR);
  conv2_qkv_k<<<8192, 256, 0, stream>>>(tL, tR, x_left, x_right, rb_w2, rb_b2,
                                        qkv_w, qkv_b, stats,
                                        qnL, qnR, knL, knR, vnL, vnR);
  attn_k<<<4096, 256, 0, stream>>>(qnL, qnR, knL, knR, vnL, vnR,
                                   d_left, d_right, x_left, x_right,
                                   out_left, out_right);
}